// Round 12
// baseline (685.434 us; speedup 1.0000x reference)
//
#include <hip/hip_runtime.h>
#include <hip/hip_bf16.h>
#include <math.h>

typedef __hip_bfloat16 bf16;
typedef __attribute__((ext_vector_type(8))) short short8;
typedef __attribute__((ext_vector_type(4))) short short4v;
typedef __attribute__((ext_vector_type(4))) float f32x4;

__device__ __forceinline__ void gload16(const bf16* g, bf16* l) {
  __builtin_amdgcn_global_load_lds((const __attribute__((address_space(1))) void*)(g),
                                   (__attribute__((address_space(3))) void*)(l), 16, 0, 0);
}
__device__ __forceinline__ float bfu2f(unsigned short u) {
  union { unsigned u; float f; } c; c.u = ((unsigned)u) << 16; return c.f;
}
__device__ __forceinline__ short bf2s(float v) {
  union { bf16 h; short s; } c; c.h = __float2bfloat16(v); return c.s;
}
__device__ __forceinline__ short4v packbf4(f32x4 v) {
  short4v o;
  o[0] = bf2s(v[0]); o[1] = bf2s(v[1]); o[2] = bf2s(v[2]); o[3] = bf2s(v[3]);
  return o;
}
__device__ __forceinline__ float geluf(float x) {
  return 0.5f * x * (1.f + tanhf(0.79788456080286535f * (x + 0.044715f * x * x * x)));
}

// ---------------------------------------------------------------------------
// Fused input preprocessing. Block ranges:
//   [0,29952)        prepack: fp32 [rows][sc] -> bf16 [rows][dc] (+opt col scale)
//   [29952,40192)    im2col (K padded to 640, 8 elems/thread)
//   [40192,40960)    s12 ca_kw (nkv): s1v/s2v (768)
//   [40960,41088)    LN(latents) -> q_ln (rows 64..127 zeroed)
//   [41088,41097)    concat3 SA biases -> sab_cat
//   [41097,44169)    s12 m1_w (no):  s1m/s2m (3072)
//   [44169,45705)    s12 f1_w (n1):  s1f/s2f (1536)
// ---------------------------------------------------------------------------
struct Seg { const float* src; bf16* dst; int rows, sc, dc; const float* scale; };
struct Segs { Seg s[13]; };

__global__ __launch_bounds__(256) void preproc_kernel(
    Segs segs,
    const float* __restrict__ frames, bf16* __restrict__ imcol,
    const float* __restrict__ kw, const float* __restrict__ nkv_g,
    const float* __restrict__ nkv_b, const float* __restrict__ kb,
    float* __restrict__ s1, float* __restrict__ s2,
    const float* __restrict__ latents, const float* __restrict__ nq_g,
    const float* __restrict__ nq_b, bf16* __restrict__ q_ln,
    const float* __restrict__ ba, const float* __restrict__ bb,
    const float* __restrict__ bc, float* __restrict__ sab_cat,
    const float* __restrict__ m1w, const float* __restrict__ no_g,
    const float* __restrict__ no_b, const float* __restrict__ m1b,
    float* __restrict__ s1m, float* __restrict__ s2m,
    const float* __restrict__ f1w, const float* __restrict__ n1_g,
    const float* __restrict__ n1_b, const float* __restrict__ f1b,
    float* __restrict__ s1f, float* __restrict__ s2f) {
  __shared__ float red[16];
  int b = blockIdx.x, tid = threadIdx.x;
  if (b < 29952) {
    Seg sg = segs.s[b / 2304];
    int bx = b % 2304;
    long long total = (long long)sg.rows * sg.dc;
    for (long long idx = (long long)bx * 256 + tid; idx < total; idx += 2304LL * 256) {
      int r = (int)(idx / sg.dc), c = (int)(idx % sg.dc);
      float v = (c < sg.sc) ? sg.src[(long long)r * sg.sc + c] : 0.f;
      if (sg.scale && c < sg.sc) v *= sg.scale[c];
      sg.dst[idx] = __float2bfloat16(v);
    }
    return;
  }
  if (b < 40192) {
    unsigned idx8 = (unsigned)(b - 29952) * 256u + tid;  // < 32768*80 exactly
    unsigned m = idx8 / 80u;
    unsigned k0 = (idx8 % 80u) * 8u;
    unsigned n = m >> 8;
    unsigned p = m & 255u;
    unsigned py = p >> 4, px = p & 15u;
    const float* fb = frames + ((size_t)n * 3u) * 224u * 224u +
                      (size_t)py * 14u * 224u + px * 14u;
    short8 o;
    #pragma unroll
    for (int e = 0; e < 8; ++e) {
      unsigned k = k0 + e;
      float v = 0.f;
      if (k < 588u) {
        unsigned c = k / 196u, r = k % 196u;
        unsigned i = r / 14u, j = r % 14u;
        v = fb[((size_t)c * 224u + i) * 224u + j];
      }
      o[e] = bf2s(v);
    }
    *(short8*)(imcol + (size_t)m * 640u + k0) = o;
    return;
  }
  // s12-style reductions (three weight matrices) and small roles
  const float* wsrc = nullptr; const float* gv = nullptr; const float* bv = nullptr;
  const float* bias = nullptr; float* o1 = nullptr; float* o2 = nullptr;
  int j = -1;
  if (b < 40960) {
    j = b - 40192; wsrc = kw; gv = nkv_g; bv = nkv_b; bias = kb; o1 = s1; o2 = s2;
  } else if (b < 41088) {
    int row = b - 40960;
    size_t base = (size_t)row * 768;
    if (row >= 64) {
      for (int i = 0; i < 3; ++i) q_ln[base + tid + i * 256] = __float2bfloat16(0.f);
      return;
    }
    float x[3];
    for (int i = 0; i < 3; ++i) x[i] = latents[base + tid + i * 256];
    float s = x[0] + x[1] + x[2];
    float sq = x[0] * x[0] + x[1] * x[1] + x[2] * x[2];
    for (int off = 32; off; off >>= 1) {
      s += __shfl_down(s, off);
      sq += __shfl_down(sq, off);
    }
    int w = tid >> 6;
    if ((tid & 63) == 0) { red[w] = s; red[4 + w] = sq; }
    __syncthreads();
    if (tid == 0) {
      red[0] = red[0] + red[1] + red[2] + red[3];
      red[4] = red[4] + red[5] + red[6] + red[7];
    }
    __syncthreads();
    float mean = red[0] * (1.f / 768.f);
    float var = red[4] * (1.f / 768.f) - mean * mean;
    float rs = rsqrtf(var + 1e-5f);
    for (int i = 0; i < 3; ++i) {
      int c = tid + i * 256;
      q_ln[base + c] = __float2bfloat16((x[i] - mean) * rs * nq_g[c] + nq_b[c]);
    }
    return;
  } else if (b < 41097) {
    int i = (b - 41088) * 256 + tid;
    if (i < 2304)
      sab_cat[i] = i < 768 ? ba[i] : (i < 1536 ? bb[i - 768] : bc[i - 1536]);
    return;
  } else if (b < 44169) {
    j = b - 41097; wsrc = m1w; gv = no_g; bv = no_b; bias = m1b; o1 = s1m; o2 = s2m;
  } else {
    j = b - 44169; wsrc = f1w; gv = n1_g; bv = n1_b; bias = f1b; o1 = s1f; o2 = s2f;
  }
  {
    const float* wr_ = wsrc + (size_t)j * 768;
    float a = 0.f, c = 0.f;
    #pragma unroll
    for (int i = 0; i < 3; ++i) {
      int d = tid + i * 256;
      float wv = wr_[d];
      a += wv * gv[d];
      c += wv * bv[d];
    }
    for (int off = 32; off; off >>= 1) { a += __shfl_down(a, off); c += __shfl_down(c, off); }
    int w = tid >> 6;
    if ((tid & 63) == 0) { red[w] = a; red[8 + w] = c; }
    __syncthreads();
    if (tid == 0) {
      o1[j] = red[0] + red[1] + red[2] + red[3];
      o2[j] = red[8] + red[9] + red[10] + red[11] + bias[j];
    }
  }
}

// per-row mean / rsqrt(var+eps) of bf16 [rows][768]; 1 wave per row
__global__ __launch_bounds__(256) void rowstats_kernel(const bf16* __restrict__ x,
                                                       float* __restrict__ mu,
                                                       float* __restrict__ rs) {
  int row = blockIdx.x * 4 + (threadIdx.x >> 6);
  int lane = threadIdx.x & 63;
  const unsigned short* p = (const unsigned short*)(x + (size_t)row * 768);
  float s = 0.f, sq = 0.f;
  #pragma unroll
  for (int i = 0; i < 3; ++i) {
    ushort4 v = *(const ushort4*)(p + lane * 4 + i * 256);
    float f0 = bfu2f(v.x), f1 = bfu2f(v.y), f2 = bfu2f(v.z), f3 = bfu2f(v.w);
    s += f0 + f1 + f2 + f3;
    sq += f0 * f0 + f1 * f1 + f2 * f2 + f3 * f3;
  }
  for (int off = 32; off; off >>= 1) { s += __shfl_down(s, off); sq += __shfl_down(sq, off); }
  if (lane == 0) {
    float m = s * (1.f / 768.f);
    float var = sq * (1.f / 768.f) - m * m;
    mu[row] = m;
    rs[row] = rsqrtf(var + 1e-5f);
  }
}

// ---------------------------------------------------------------------------
// LayerNorm over D=768 (final n2 only)
// ---------------------------------------------------------------------------
__global__ __launch_bounds__(256) void ln_kernel(const float* __restrict__ inF,
                                                 const float* __restrict__ g,
                                                 const float* __restrict__ b,
                                                 float* __restrict__ outF) {
  int row = blockIdx.x;
  int tid = threadIdx.x;
  __shared__ float red[8];
  size_t base = (size_t)row * 768;
  float x[3];
  for (int i = 0; i < 3; ++i) x[i] = inF[base + tid + i * 256];
  float s = x[0] + x[1] + x[2];
  float sq = x[0] * x[0] + x[1] * x[1] + x[2] * x[2];
  for (int off = 32; off; off >>= 1) {
    s += __shfl_down(s, off);
    sq += __shfl_down(sq, off);
  }
  int w = tid >> 6;
  if ((tid & 63) == 0) { red[w] = s; red[4 + w] = sq; }
  __syncthreads();
  if (tid == 0) {
    red[0] = red[0] + red[1] + red[2] + red[3];
    red[4] = red[4] + red[5] + red[6] + red[7];
  }
  __syncthreads();
  float mean = red[0] * (1.f / 768.f);
  float var = red[4] * (1.f / 768.f) - mean * mean;
  float rs = rsqrtf(var + 1e-5f);
  for (int i = 0; i < 3; ++i) {
    int c = tid + i * 256;
    outF[base + c] = (x[i] - mean) * rs * g[c] + b[c];
  }
}

// ---------------------------------------------------------------------------
// 256x256 bf16 MFMA GEMM — counted-vmcnt phase-split (T3+T4+T5), verified R11.
// act: 0=none, 3=split-KV.
// ---------------------------------------------------------------------------
__global__ __launch_bounds__(512, 2) void gemm256(
    const bf16* __restrict__ A, const bf16* __restrict__ Bw,
    const float* __restrict__ bias,
    bf16* __restrict__ outB,
    int M, int N, int K, int act,
    const float* __restrict__ rowMu, const float* __restrict__ rowRs,
    const float* __restrict__ s1, const float* __restrict__ s2,
    bf16* __restrict__ outB2) {
  __shared__ __align__(16) bf16 As[4][8192];   // 4 x 16KB
  __shared__ __align__(16) bf16 Bs[4][8192];
  int tid = threadIdx.x;
  int nwg = gridDim.x * gridDim.y;
  int orig = blockIdx.y * gridDim.x + blockIdx.x;
  int xcd = orig & 7, loc = orig >> 3;
  int qq = nwg >> 3, rr = nwg & 7;
  int swz = (xcd < rr) ? (xcd * (qq + 1) + loc) : (rr * (qq + 1) + (xcd - rr) * qq + loc);
  int m0 = (swz / gridDim.x) * 256, n0 = (swz % gridDim.x) * 256;

  int lane = tid & 63, w = tid >> 6;      // 8 waves
  int wr = w >> 2, wc = w & 3;            // 2 x 4 wave grid
  int l15 = lane & 15, lq = lane >> 4;

  f32x4 acc[8][4] = {};

  #define STAGEH(buf, kt, part)                                                \
    {                                                                          \
      int koct_ = w >> 1;                                                      \
      int row0_ = (w & 1) * 64 + ((part) & 1) * 128;                           \
      if ((part) < 2)                                                          \
        gload16(A + (size_t)(m0 + row0_ + lane) * K + (kt) + koct_ * 8,        \
                &As[buf][(koct_ * 256 + row0_) * 8]);                          \
      else                                                                     \
        gload16(Bw + (size_t)(n0 + row0_ + lane) * K + (kt) + koct_ * 8,       \
                &Bs[buf][(koct_ * 256 + row0_) * 8]);                          \
    }

  int T = K >> 5;
  #pragma unroll
  for (int p = 0; p < 4; ++p) STAGEH(0, 0, p);
  #pragma unroll
  for (int p = 0; p < 4; ++p) STAGEH(1, 32, p);
  STAGEH(2, 64, 0);
  STAGEH(2, 64, 1);
  asm volatile("s_waitcnt vmcnt(6)" ::: "memory");
  __builtin_amdgcn_s_barrier();

  for (int t = 0; t < T; ++t) {
    int bufc = t & 3, bufn2 = (t + 2) & 3, bufn3 = (t + 3) & 3;
    int kt2 = (t + 2) << 5, kt3 = (t + 3) << 5;
    short8 af[4], bfr[4];
    #pragma unroll
    for (int ni = 0; ni < 4; ++ni)
      bfr[ni] = *(const short8*)(&Bs[bufc][(lq * 256 + wc * 64 + ni * 16 + l15) * 8]);
    #pragma unroll
    for (int mi = 0; mi < 4; ++mi)
      af[mi] = *(const short8*)(&As[bufc][(lq * 256 + wr * 128 + mi * 16 + l15) * 8]);
    if (t + 2 < T) { STAGEH(bufn2, kt2, 2); STAGEH(bufn2, kt2, 3); }
    __builtin_amdgcn_s_barrier();
    asm volatile("" ::: "memory");
    __builtin_amdgcn_s_setprio(1);
    #pragma unroll
    for (int mi = 0; mi < 4; ++mi)
      #pragma unroll
      for (int ni = 0; ni < 4; ++ni)
        acc[mi][ni] = __builtin_amdgcn_mfma_f32_16x16x32_bf16(bfr[ni], af[mi],
                                                              acc[mi][ni], 0, 0, 0);
    __builtin_amdgcn_s_setprio(0);
    asm volatile("" ::: "memory");
    __builtin_amdgcn_s_barrier();
    #pragma unroll
    for (int mi = 0; mi < 4; ++mi)
      af[mi] = *(const short8*)(&As[bufc][(lq * 256 + wr * 128 + 64 + mi * 16 + l15) * 8]);
    if (t + 3 < T) { STAGEH(bufn3, kt3, 0); STAGEH(bufn3, kt3, 1); }
    if (t + 3 < T) {
      asm volatile("s_waitcnt vmcnt(6)" ::: "memory");
    } else if (t + 2 < T) {
      asm volatile("s_waitcnt vmcnt(4)" ::: "memory");
    } else if (t + 1 < T) {
      asm volatile("s_waitcnt vmcnt(0)" ::: "memory");
    }
    __builtin_amdgcn_s_barrier();
    asm volatile("" ::: "memory");
    __builtin_amdgcn_s_setprio(1);
    #pragma unroll
    for (int mi = 0; mi < 4; ++mi)
      #pragma unroll
      for (int ni = 0; ni < 4; ++ni)
        acc[4 + mi][ni] = __builtin_amdgcn_mfma_f32_16x16x32_bf16(bfr[ni], af[mi],
                                                                  acc[4 + mi][ni], 0, 0, 0);
    __builtin_amdgcn_s_setprio(0);
    asm volatile("" ::: "memory");
    __builtin_amdgcn_s_barrier();
  }
  #undef STAGEH

  // ---- staged, coalesced epilogue ----
  bf16* ldsflat = (bf16*)As;
  bf16* ep = ldsflat + w * 1152;
  int rlo = lane >> 3, cg = lane & 7;

  if (act == 3) {
    int c0w = n0 + wc * 64;
    bool isV = (c0w < 768);
    bf16* dst = isV ? outB : outB2;
    int colbase = isV ? c0w : (c0w - 768);
    f32x4 bv[4], a1[4], a2[4];
    #pragma unroll
    for (int ni = 0; ni < 4; ++ni) {
      int cc = colbase + ni * 16 + lq * 4;
      if (isV) bv[ni] = *(const f32x4*)(bias + cc);
      else { a1[ni] = *(const f32x4*)(s1 + cc); a2[ni] = *(const f32x4*)(s2 + cc); }
    }
    #pragma unroll
    for (int mi = 0; mi < 8; ++mi) {
      int roww = m0 + wr * 128 + mi * 16 + l15;
      float rs_ = 0.f, mu_ = 0.f;
      if (!isV) { rs_ = rowRs[roww]; mu_ = rowMu[roww]; }
      #pragma unroll
      for (int ni = 0; ni < 4; ++ni) {
        f32x4 v;
        if (isV) v = acc[mi][ni] + bv[ni];
        else {
          #pragma unroll
          for (int j = 0; j < 4; ++j)
            v[j] = rs_ * (acc[mi][ni][j] - mu_ * a1[ni][j]) + a2[ni][j];
        }
        *(short4v*)(ep + l15 * 72 + ni * 16 + lq * 4) = packbf4(v);
      }
      asm volatile("s_waitcnt lgkmcnt(0)" ::: "memory");
      #pragma unroll
      for (int p = 0; p < 2; ++p) {
        int r = p * 8 + rlo;
        short8 d = *(const short8*)(ep + r * 72 + cg * 8);
        int rg = m0 + wr * 128 + mi * 16 + r;
        *(short8*)(dst + (size_t)rg * 768 + colbase + cg * 8) = d;
      }
      asm volatile("s_waitcnt lgkmcnt(0)" ::: "memory");
    }
    return;
  }

  {
    int c0w = n0 + wc * 64;
    f32x4 bv[4] = {};
    if (bias) {
      #pragma unroll
      for (int ni = 0; ni < 4; ++ni)
        bv[ni] = *(const f32x4*)(bias + c0w + ni * 16 + lq * 4);
    }
    #pragma unroll
    for (int mi = 0; mi < 8; ++mi) {
      #pragma unroll
      for (int ni = 0; ni < 4; ++ni) {
        f32x4 v = acc[mi][ni] + bv[ni];
        *(short4v*)(ep + l15 * 72 + ni * 16 + lq * 4) = packbf4(v);
      }
      asm volatile("s_waitcnt lgkmcnt(0)" ::: "memory");
      #pragma unroll
      for (int p = 0; p < 2; ++p) {
        int r = p * 8 + rlo;
        short8 d = *(const short8*)(ep + r * 72 + cg * 8);
        int rg = m0 + wr * 128 + mi * 16 + r;
        *(short8*)(outB + (size_t)rg * N + c0w + cg * 8) = d;
      }
      asm volatile("s_waitcnt lgkmcnt(0)" ::: "memory");
    }
  }
}

// ---------------------------------------------------------------------------
// 128x128 bf16 MFMA GEMM (small/medium shapes).
// act: 0=none, 1=gelu, 2=relu,
//      4=fused-input-LN (rowMu/rowRs/s1/s2) + gelu  -> outB
//      5=fused-input-LN + relu                      -> outB
//      6=bias + LN-residual from yraw/gamma/beta    -> outF
// ---------------------------------------------------------------------------
__global__ __launch_bounds__(256) void gemm_bf16(
    const bf16* __restrict__ A, const bf16* __restrict__ Bw,
    const float* __restrict__ bias, const float* __restrict__ resid,
    float* __restrict__ outF, bf16* __restrict__ outB,
    int M, int N, int K, int act,
    const float* __restrict__ rowMu, const float* __restrict__ rowRs,
    const float* __restrict__ s1, const float* __restrict__ s2,
    const float* __restrict__ yraw, const float* __restrict__ gamma,
    const float* __restrict__ beta) {
  __shared__ __align__(16) bf16 As[2][4096];
  __shared__ __align__(16) bf16 Bs[2][4096];
  int tid = threadIdx.x;
  int nwg = gridDim.x * gridDim.y;
  int orig = blockIdx.y * gridDim.x + blockIdx.x;
  int xcd = orig & 7, loc = orig >> 3;
  int qq = nwg >> 3, rr = nwg & 7;
  int swz = (xcd < rr) ? (xcd * (qq + 1) + loc) : (rr * (qq + 1) + (xcd - rr) * qq + loc);
  int m0 = (swz / gridDim.x) * 128, n0 = (swz % gridDim.x) * 128;

  int lane = tid & 63, w = tid >> 6;
  int wr = w >> 1, wc = w & 1;
  int l15 = lane & 15, lq = lane >> 4;
  const bf16* Abase = A + (size_t)m0 * K + w * 8;
  const bf16* Bbase = Bw + (size_t)n0 * K + w * 8;
  f32x4 acc[4][4] = {};

  int nt = K >> 5;
  #pragma unroll
  for (int i = 0; i < 2; ++i) {
    int r = i * 64 + lane;
    gload16(Abase + (size_t)r * K, &As[0][(w * 2 + i) * 512]);
    gload16(Bbase + (size_t)r * K, &Bs[0][(w * 2 + i) * 512]);
  }
  for (int t = 0; t < nt; ++t) {
    int cur = t & 1;
    if (t + 1 < nt) {
      int kt = (t + 1) << 5;
      #pragma unroll
      for (int i = 0; i < 2; ++i) {
        int r = i * 64 + lane;
        gload16(Abase + (size_t)r * K + kt, &As[cur ^ 1][(w * 2 + i) * 512]);
        gload16(Bbase + (size_t)r * K + kt, &Bs[cur ^ 1][(w * 2 + i) * 512]);
      }
      asm volatile("s_waitcnt vmcnt(4)" ::: "memory");
    } else {
      asm volatile("s_waitcnt vmcnt(0)" ::: "memory");
    }
    __builtin_amdgcn_s_barrier();
    asm volatile("" ::: "memory");
    const bf16* Ab = &As[cur][lq * 1024];
    const bf16* Bb = &Bs[cur][lq * 1024];
    short8 af[4], bfr[4];
    #pragma unroll
    for (int mi = 0; mi < 4; ++mi)
      af[mi] = *(const short8*)(Ab + (wr * 64 + mi * 16 + l15) * 8);
    #pragma unroll
    for (int ni = 0; ni < 4; ++ni)
      bfr[ni] = *(const short8*)(Bb + (wc * 64 + ni * 16 + l15) * 8);
    __builtin_amdgcn_s_setprio(1);
    #pragma unroll
    for (int mi = 0; mi < 4; ++mi)
      #pragma unroll
      for (int ni = 0; ni < 4; ++ni)
        acc[mi][ni] = __builtin_amdgcn_mfma_f32_16x16x32_bf16(bfr[ni], af[mi],
                                                              acc[mi][ni], 0, 0, 0);
    __builtin_amdgcn_s_setprio(0);
    asm volatile("" ::: "memory");
    __builtin_amdgcn_s_barrier();
  }

  if (act == 4 || act == 5) {
    #pragma unroll
    for (int ni = 0; ni < 4; ++ni) {
      int c0 = n0 + wc * 64 + ni * 16 + lq * 4;
      f32x4 a1 = *(const f32x4*)(s1 + c0);
      f32x4 a2 = *(const f32x4*)(s2 + c0);
      #pragma unroll
      for (int mi = 0; mi < 4; ++mi) {
        int row = m0 + wr * 64 + mi * 16 + l15;
        float rs_ = rowRs[row], mu_ = rowMu[row];
        f32x4 v;
        #pragma unroll
        for (int j = 0; j < 4; ++j) {
          float x = rs_ * (acc[mi][ni][j] - mu_ * a1[j]) + a2[j];
          v[j] = (act == 4) ? geluf(x) : fmaxf(x, 0.f);
        }
        *(short4v*)(outB + (size_t)row * N + c0) = packbf4(v);
      }
    }
    return;
  }
  if (act == 6) {
    #pragma unroll
    for (int ni = 0; ni < 4; ++ni) {
      int c0 = n0 + wc * 64 + ni * 16 + lq * 4;
      f32x4 bv = *(const f32x4*)(bias + c0);
      f32x4 gm = *(const f32x4*)(gamma + c0);
      f32x4 bt = *(const f32x4*)(beta + c0);
      #pragma unroll
      for (int mi = 0; mi < 4; ++mi) {
        int row = m0 + wr * 64 + mi * 16 + l15;
        float rs_ = rowRs[row], mu_ = rowMu[row];
        size_t idx = (size_t)row * N + c0;
        f32x4 yv = *(const f32x4*)(yraw + idx);
        f32x4 v;
        #pragma unroll
        for (int j = 0; j < 4; ++j)
          v[j] = acc[mi][ni][j] + bv[j] + (rs_ * (yv[j] - mu_) * gm[j] + bt[j]);
        *(f32x4*)(outF + idx) = v;
      }
    }
    return;
  }

  #pragma unroll
  for (int ni = 0; ni < 4; ++ni) {
    int c0 = n0 + wc * 64 + ni * 16 + lq * 4;
    f32x4 bv = {};
    if (bias) bv = *(const f32x4*)(bias + c0);
    #pragma unroll
    for (int mi = 0; mi < 4; ++mi) {
      int row = m0 + wr * 64 + mi * 16 + l15;
      f32x4 v = acc[mi][ni] + bv;
      if (act == 1) {
        #pragma unroll
        for (int j = 0; j < 4; ++j) v[j] = geluf(v[j]);
      } else if (act == 2) {
        #pragma unroll
        for (int j = 0; j < 4; ++j) v[j] = fmaxf(v[j], 0.f);
      }
      size_t idx = (size_t)row * N + c0;
      if (resid) v += *(const f32x4*)(resid + idx);
      if (outF) *(f32x4*)(outF + idx) = v;
      if (outB) *(short4v*)(outB + idx) = packbf4(v);
    }
  }
}

// ---------------------------------------------------------------------------
// Flash attention (non-split, used for SA). HD=96, NH=8.
// ---------------------------------------------------------------------------
__global__ __launch_bounds__(256) void flash_kernel(
    const bf16* __restrict__ Q, const bf16* __restrict__ Kp,
    const bf16* __restrict__ V, bf16* __restrict__ O,
    int Lk, int qRPB, int kRPB, int oRPB, int ld) {
  const float scale = 0.10206207261596575f;  // 1/sqrt(96)
  __shared__ bf16 Vt[96 * 72];
  __shared__ bf16 Ps[4 * 16 * 72];
  int tid = threadIdx.x, lane = tid & 63, w = tid >> 6;
  int l15 = lane & 15, lq = lane >> 4;
  int b = blockIdx.z, h = blockIdx.y, qt = blockIdx.x;
  int qbase = b * qRPB + qt * 64 + w * 16;
  int kbase = b * kRPB;
  int obase = b * oRPB + qt * 64 + w * 16;
  int ch = h * 96;

  short8 aQ[3];
  #pragma unroll
  for (int kd = 0; kd < 3; ++kd)
    aQ[kd] = *(const short8*)(Q + (size_t)(qbase + l15) * ld + ch + kd * 32 + lq * 8);

  f32x4 oacc[6] = {};
  float mrun[4] = {-1e30f, -1e30f, -1e30f, -1e30f};
  float lrun[4] = {0.f, 0.f, 0.f, 0.f};

  for (int kc = 0; kc < Lk; kc += 64) {
    for (int u = tid; u < 768; u += 256) {
      int kk = u / 12, dc = u % 12;
      short8 v = *(const short8*)(V + (size_t)(kbase + kc + kk) * ld + ch + dc * 8);
      const bf16* pv = (const bf16*)&v;
      #pragma unroll
      for (int e = 0; e < 8; ++e) Vt[(dc * 8 + e) * 72 + kk] = pv[e];
    }
    __syncthreads();

    f32x4 sacc[4] = {};
    #pragma unroll
    for (int ni = 0; ni < 4; ++ni)
      #pragma unroll
      for (int kd = 0; kd < 3; ++kd) {
        short8 bK = *(const short8*)(Kp + (size_t)(kbase + kc + ni * 16 + l15) * ld +
                                     ch + kd * 32 + lq * 8);
        sacc[ni] = __builtin_amdgcn_mfma_f32_16x16x32_bf16(aQ[kd], bK, sacc[ni], 0, 0, 0);
      }
    #pragma unroll
    for (int ni = 0; ni < 4; ++ni)
      #pragma unroll
      for (int j = 0; j < 4; ++j) sacc[ni][j] *= scale;

    float al[4];
    #pragma unroll
    for (int j = 0; j < 4; ++j) {
      float mx = fmaxf(fmaxf(sacc[0][j], sacc[1][j]), fmaxf(sacc[2][j], sacc[3][j]));
      #pragma unroll
      for (int off = 1; off < 16; off <<= 1) mx = fmaxf(mx, __shfl_xor(mx, off));
      float mnew = fmaxf(mrun[j], mx);
      float alpha = __expf(mrun[j] - mnew);
      float rsum = 0.f;
      #pragma unroll
      for (int ni = 0; ni < 4; ++ni) {
        float p = __expf(sacc[ni][j] - mnew);
        sacc[ni][j] = p;
        rsum += p;
      }
      #pragma unroll
      for (int off = 1; off < 16; off <<= 1) rsum += __shfl_xor(rsum, off);
      lrun[j] = lrun[j] * alpha + rsum;
      mrun[j] = mnew;
      al[j] = alpha;
    }

    #pragma unroll
    for (int ni = 0; ni < 4; ++ni)
      #pragma unroll
      for (int j = 0; j < 4; ++j)
        Ps[(w * 16 + lq * 4 + j) * 72 + ni * 16 + l15] = __float2bfloat16(sacc[ni][j]);
    #pragma unroll
    for (int t = 0; t < 6; ++t)
      #pragma unroll
      for (int j = 0; j < 4; ++j) oacc[t][j] *= al[j];
    short8 aP[2];
    #pragma unroll
    for (int ks = 0; ks < 2; ++ks)
      aP[ks] = *(const short8*)(&Ps[(w * 16 + l15) * 72 + ks * 32 + lq * 8]);
    #pragma unroll
    for (int t = 0; t < 6; ++t)
      #pragma unroll
      for (int ks = 0; ks < 2; ++ks) {
        short8 bV = *(const short8*)(&Vt[(t * 16 + l15) * 72 + ks * 32 + lq * 8]);
        oacc[t] = __builtin_amdgcn_mfma_f32_16x16x32_bf16(aP[ks], bV, oacc[t], 0, 0, 0);
      }
    __syncthreads();
  }

  #pragma unroll
  for (int t = 0; t < 6; ++t)
    #pragma unroll
    for (int j = 0; j < 4; ++j) {
      int row = obase + lq * 4 + j;
      int col = ch + t * 16 + l15;
      O[(size_t)row * 768 + col] = __float2bfloat16(oacc[t][j] / lrun[j]);
    }
}

// ---------------------------------------------------------------------------
// Split-K flash for cross-attention (broadcast latent Q, 64 rows/batch).
// Opart stored bf16 (unnormalized partials) to fit 16 splits in the region.
// ---------------------------------------------------------------------------
__global__ __launch_bounds__(256) void flash_split_kernel(
    const bf16* __restrict__ Q, const bf16* __restrict__ Kp,
    const bf16* __restrict__ V, bf16* __restrict__ Opart,
    float* __restrict__ Mpart, float* __restrict__ Lpart,
    int splitLen, int kRPB, int nsplit) {
  const float scale = 0.10206207261596575f;
  __shared__ bf16 Vt[96 * 72];
  __shared__ bf16 Ps[4 * 16 * 72];
  int tid = threadIdx.x, lane = tid & 63, w = tid >> 6;
  int l15 = lane & 15, lq = lane >> 4;
  int s = blockIdx.x, h = blockIdx.y, b = blockIdx.z;
  int kbase = b * kRPB + s * splitLen;
  int ch = h * 96;

  short8 aQ[3];
  #pragma unroll
  for (int kd = 0; kd < 3; ++kd)
    aQ[kd] = *(const short8*)(Q + (size_t)(w * 16 + l15) * 768 + ch + kd * 32 + lq * 8);

  f32x4 oacc[6] = {};
  float mrun[4] = {-1e30f, -1e30f, -1e30f, -1e30f};
  float lrun[4] = {0.f, 0.f, 0.f, 0.f};

  for (int kc = 0; kc < splitLen; kc += 64) {
    for (int u = tid; u < 768; u += 256) {
      int kk = u / 12, dc = u % 12;
      short8 v = *(const short8*)(V + (size_t)(kbase + kc + kk) * 768 + ch + dc * 8);
      const bf16* pv = (const bf16*)&v;
      #pragma unroll
      for (int e = 0; e < 8; ++e) Vt[(dc * 8 + e) * 72 + kk] = pv[e];
    }
    __syncthreads();

    f32x4 sacc[4] = {};
    #pragma unroll
    for (int ni = 0; ni < 4; ++ni)
      #pragma unroll
      for (int kd = 0; kd < 3; ++kd) {
        short8 bK = *(const short8*)(Kp + (size_t)(kbase + kc + ni * 16 + l15) * 768 +
                                     ch + kd * 32 + lq * 8);
        sacc[ni] = __builtin_amdgcn_mfma_f32_16x16x32_bf16(aQ[kd], bK, sacc[ni], 0, 0, 0);
      }
    #pragma unroll
    for (int ni = 0; ni < 4; ++ni)
      #pragma unroll
      for (int j = 0; j < 4; ++j) sacc[ni][j] *= scale;

    float al[4];
    #pragma unroll
    for (int j = 0; j < 4; ++j) {
      float mx = fmaxf(fmaxf(sacc[0][j], sacc[1][j]), fmaxf(sacc[2][j], sacc[3][j]));
      #pragma unroll
      for (int off = 1; off < 16; off <<= 1) mx = fmaxf(mx, __shfl_xor(mx, off));
      float mnew = fmaxf(mrun[j], mx);
      float alpha = __expf(mrun[j] - mnew);
      float rsum = 0.f;
      #pragma unroll
      for (int ni = 0; ni < 4; ++ni) {
        float p = __expf(sacc[ni][j] - mnew);
        sacc[ni][j] = p;
        rsum += p;
      }
      #pragma unroll
      for (int off = 1; off < 16; off <<= 1) rsum += __shfl_xor(rsum, off);
      lrun[j] = lrun[j] * alpha + rsum;
      mrun[j] = mnew;
      al[j] = alpha;
    }

    #pragma unroll
    for (int ni = 0; ni < 4; ++ni)
      #pragma unroll
      for (int j = 0; j < 4; ++j)
        Ps[(w * 16 + lq * 4 + j) * 72 + ni * 16 + l15] = __float2bfloat16(sacc[ni][j]);
    #pragma unroll
    for (int t = 0; t < 6; ++t)
      #pragma unroll
      for (int j = 0; j < 4; ++j) oacc[t][j] *= al[j];
    short8 aP[2];
    #pragma unroll
    for (int ks = 0; ks < 2; ++ks)
      aP[ks] = *(const short8*)(&Ps[(w * 16 + l15) * 72 + ks * 32 + lq * 8]);
    #pragma unroll
    for (int t = 0; t < 6; ++t)
      #pragma unroll
      for (int ks = 0; ks < 2; ++ks) {
        short8 bV = *(const short8*)(&Vt[(t * 16 + l15) * 72 + ks * 32 + lq * 8]);
        oacc[t] = __builtin_amdgcn_mfma_f32_16x16x32_bf16(aP[ks], bV, oacc[t], 0, 0, 0);
      }
    __syncthreads();
  }

  int orow = b * 64 + w * 16;
  #pragma unroll
  for (int t = 0; t < 6; ++t)
    #pragma unroll
    for (int j = 0; j < 4; ++j)
      Opart[(size_t)(s * 1024 + orow + lq * 4 + j) * 768 + ch + t * 16 + l15] =
          __float2bfloat16(oacc[t][j]);
  if (l15 == 0) {
    #pragma unroll
    for (int j = 0; j < 4; ++j) {
      int qqi = w * 16 + lq * 4 + j;
      int mi = ((s * 16 + b) * 8 + h) * 64 + qqi;
      Mpart[mi] = mrun[j];
      Lpart[mi] = lrun[j];
    }
  }
}

__global__ __launch_bounds__(256) void flash_merge_kernel(
    const bf16* __restrict__ Opart, const float* __restrict__ Mpart,
    const float* __restrict__ Lpart, bf16* __restrict__ O, int nsplit) {
  int row = blockIdx.x;   // b*64+q
  int tid = threadIdx.x;
  int c0 = tid * 3;
  int b = row >> 6, q = row & 63;
  int h = c0 / 96;
  float m = -1e30f;
  for (int s = 0; s < nsplit; ++s)
    m = fmaxf(m, Mpart[((s * 16 + b) * 8 + h) * 64 + q]);
  float l = 0.f, o0 = 0.f, o1 = 0.f, o2 = 0.f;
  const unsigned short* opu = (const unsigned short*)Opart;
  for (int s = 0; s < nsplit; ++s) {
    int mi = ((s * 16 + b) * 8 + h) * 64 + q;
    float ws = __expf(Mpart[mi] - m);
    l += ws * Lpart[mi];
    size_t ob = (size_t)(s * 1024 + row) * 768 + c0;
    o0 += ws * bfu2f(opu[ob]);
    o1 += ws * bfu2f(opu[ob + 1]);
    o2 += ws * bfu2f(opu[ob + 2]);
  }
  float inv = 1.f / l;
  size_t ob = (size_t)row * 768 + c0;
  O[ob]     = __float2bfloat16(o0 * inv);
  O[ob + 1] = __float2bfloat16(o1 * inv);
  O[ob + 2] = __float2bfloat16(o2 * inv);
}

// ---------------------------------------------------------------------------
extern "C" void kernel_launch(void* const* d_in, const int* in_sizes, int n_in,
                              void* d_out, int out_size, void* d_ws, size_t ws_size,
                              hipStream_t stream) {
  const float* frames = (const float*)d_in[0];
  const float* pe_w   = (const float*)d_in[1];
  const float* pe_b   = (const float*)d_in[2];
  const float* latents= (const float*)d_in[3];
  const float* ca_qw  = (const float*)d_in[4];  const float* ca_qb = (const float*)d_in[5];
  const float* ca_kw  = (const float*)d_in[6];  const float* ca_kb = (const float*)d_in[7];
  const float* ca_vw  = (const float*)d_in[8];  const float* ca_vb = (const float*)d_in[9];
  const float* ca_ow  = (const float*)d_in[10]; const float* ca_ob = (const float*)d_in[11];
  const float* nq_g   = (const float*)d_in[12]; const float* nq_b  = (const float*)d_in[13];
  const float* nkv_g  = (const float*)d_in[14]; const float* nkv_b = (const float*)d_in[15];
  const float* no_g   = (const float*)d_in[16]; const float* no_b  = (const float*)d_in[17];
  const float* m1_w   = (const float*)d_in[18]; const float* m1_b  = (const float*)d_in[19];
  const float* m2_w   = (const float*)d_in[20]; const float* m2_b  = (const float*)d_in[21];
  const float* sa_qw  = (const float*)d_in[22]; const float* sa_qb = (const float*)d_in[23];
  const float* sa_kw  = (const float*)d_in[24]; const float* sa_kb = (const float*)d_in[25];
  const float* sa_vw  = (const float*)d_in[26]; const float* sa_vb = (const float*)d_in[27];
  const float* sa_ow  = (const float*)d_in[28]; const float* sa_ob = (const float*)d_in[29];
  const float* f1_w   = (const float*)d_in[30]; const float* f1_b  = (const float*)d_in[31];
  const float* f2_w   = (const float*)d_in[32]; const float* f2_b  = (const float*)d_in[33];
  const float* n1_g   = (const float*)d_in[34]; const float* n1_b  = (const float*)d_in[35];
  const float* n2_g   = (const float*)d_in[36]; const float* n2_b  = (const float*)d_in[37];

  char* ws = (char*)d_ws;
  size_t off = 0;
  auto take = [&](size_t bytes) -> char* {
    char* p = ws + off;
    off += (bytes + 255) & ~(size_t)255;
    return p;
  };

  // persistent bf16 weights
  bf16* w_pe   = (bf16*)take((size_t)768 * 640 * 2);
  bf16* w_caq  = (bf16*)take((size_t)768 * 768 * 2);
  bf16* w_cakv = (bf16*)take((size_t)1536 * 768 * 2);  // [V(768); K'(768)] rows
  bf16* w_cao  = (bf16*)take((size_t)768 * 768 * 2);
  bf16* w_m1   = (bf16*)take((size_t)3072 * 768 * 2);  // scaled by no_g
  bf16* w_m2   = (bf16*)take((size_t)768 * 3072 * 2);
  bf16* w_saq  = (bf16*)take((size_t)768 * 768 * 2);   // contiguous with sak/sav
  bf16* w_sak  = (bf16*)take((size_t)768 * 768 * 2);
  bf16* w_sav  = (bf16*)take((size_t)768 * 768 * 2);
  bf16* w_sao  = (bf16*)take((size_t)768 * 768 * 2);
  bf16* w_f1   = (bf16*)take((size_t)1536 * 768 * 2);  // scaled by n1_g
  bf16* w_f2   = (bf16*)take((size_t)768 * 1536 * 2);
  float* sab_cat = (float*)take((size_t)2304 * 4);
  float* s1v  = (float*)take((size_t)768 * 4);
  float* s2v  = (float*)take((size_t)768 * 4);
  float* s1m  = (float*)take((size_t)3072 * 4);
  float* s2m  = (float*)take((size_t)3072 * 4);
  float* s1f  = (float*)take((size_t)1536 * 4);
  float* s2f  = (float*)take((size_t)1536 * 4);
  float* muv  = (float*)take((size_t)32768 * 4);
  float* rsv  = (float*)take((size_t)32768 * 4);
  float* muo  = (float*)take((size_t)1024 * 4);
  float* rso  = (float*)take((size_t)1024 * 4);
  float* muy  = (float*)take((size_t)1024 * 4);
  float* rsy  = (float*)take((size_t)1024 * 4);

  bf16* q_ln = (bf16*)take((size_t)128 * 768 * 2);
  bf16* qh   = (bf16*)take((size_t)128 * 768 * 2);

  bf16* kv   = (bf16*)take((size_t)32768 * 768 * 2);   // raw patch tokens
  bf16* vhkh = (bf16*)take((size_t)2 * 32768 * 768 * 2);
  bf16* vh = vhkh;
  bf16* kh = vhkh + (size_t)32768 * 768;
  bf16* imcol = vhkh;  // dead after patch GEMM, before vh/kh are written

  // union region: CA split partials (16 x bf16) / stage-2/3 activations
  const size_t REGION = (size_t)32768 * 608 * 2;  // 39,845,888
  char* region = take(REGION);
  bf16*  Opart = (bf16*)region;                           // 25,165,824 B
  float* Mpart = (float*)(region + 25165824);             //    524,288 B
  float* Lpart = (float*)(region + 25165824 + 524288);    //    524,288 B
  bf16*  attn_o = (bf16*)(region + REGION - (size_t)1024 * 768 * 2);
  size_t ro = 0;
  auto rtake = [&](size_t bytes) -> char* {
    char* p = region + ro;
    ro += (bytes + 255) & ~(size_t)255;
    return p;
  };
  float* out_f  = (float*)rtake((size_t)1024 * 768 * 4);
  bf16*  out_b  = (bf16*)rtake((size_t)1024 * 768 * 2);
  bf16*  g_b    = (bf16*)rtake((size_t)1024 * 3072 * 2);
  float* tok_f  = (float*)rtake((size_t)1024 * 768 * 4);
  bf16*  tok_b  = (bf16*)rtake((size_t)1024 * 768 * 2);
  bf16*  xqkv   = (bf16*)rtake((size_t)1024 * 2304 * 2);
  bf16*  sa_o   = (bf16*)rtake((size_t)1024 * 768 * 2);
  float* y_f    = (float*)rtake((size_t)1024 * 768 * 4);
  bf16*  y_b    = (bf16*)rtake((size_t)1024 * 768 * 2);
  bf16*  ff1    = (bf16*)rtake((size_t)1024 * 1536 * 2);
  float* z_f    = (float*)rtake((size_t)1024 * 768 * 4);
  (void)ws_size; (void)in_sizes; (void)n_in; (void)out_size;

  // 1) fused preprocessing
  Segs segs;
  segs.s[0]  = {pe_w,  w_pe,  768, 588, 640, nullptr};
  segs.s[1]  = {ca_qw, w_caq, 768, 768, 768, nullptr};
  segs.s[2]  = {ca_vw, w_cakv, 768, 768, 768, nullptr};
  segs.s[3]  = {ca_kw, w_cakv + (size_t)768 * 768, 768, 768, 768, nkv_g};
  segs.s[4]  = {ca_ow, w_cao, 768, 768, 768, nullptr};
  segs.s[5]  = {m1_w,  w_m1,  3072, 768, 768, no_g};
  segs.s[6]  = {m2_w,  w_m2,  768, 3072, 3072, nullptr};
  segs.s[7]  = {sa_qw, w_saq, 768, 768, 768, nullptr};
  segs.s[8]  = {sa_kw, w_sak, 768, 768, 768, nullptr};
  segs.s[9]  = {sa_vw, w_sav, 768, 768, 768, nullptr};
  segs.s[10] = {f1_w,  w_f1,  1536, 768, 768, n1_g};
  segs.s[11] = {f2_w,  w_f2,  768, 1536, 1536, nullptr};
  segs.s[12] = {sa_ow, w_sao, 768, 768, 768, nullptr};
  preproc_kernel<<<45705, 256, 0, stream>>>(
      segs, frames, imcol,
      ca_kw, nkv_g, nkv_b, ca_kb, s1v, s2v,
      latents, nq_g, nq_b, q_ln,
      sa_qb, sa_kb, sa_vb, sab_cat,
      m1_w, no_g, no_b, m1_b, s1m, s2m,
      f1_w, n1_g, n1_b, f1_b, s1f, s2f);

  // 2) patch-embed GEMM (256^2, phase-split) -> kv
  gemm256<<<dim3(3, 128), 512, 0, stream>>>(imcol, w_pe, pe_b, kv,
                                            32768, 768, 640, 0,
                                            nullptr, nullptr, nullptr, nullptr, nullptr);

  // 3) Q projection (small)
  gemm_bf16<<<dim3(6, 1), 256, 0, stream>>>(q_ln, w_caq, ca_qb, nullptr, nullptr, qh,
                                            128, 768, 768, 0,
                                            nullptr, nullptr, nullptr, nullptr,
                                            nullptr, nullptr, nullptr);

  // 4) per-row LN stats of kv
  rowstats_kernel<<<8192, 256, 0, stream>>>(kv, muv, rsv);

  // 5) merged V + fused-LN-K projection (256^2, phase-split) -> vh, kh
  gemm256<<<dim3(6, 128), 512, 0, stream>>>(kv, w_cakv, ca_vb, vh,
                                            32768, 1536, 768, 3,
                                            muv, rsv, s1v, s2v, kh);

  // 6) cross-attention split-K: 16 splits x 8 heads x 16 batches
  flash_split_kernel<<<dim3(16, 8, 16), 256, 0, stream>>>(qh, kh, vh, Opart, Mpart, Lpart,
                                                          128, 2048, 16);
  flash_merge_kernel<<<1024, 256, 0, stream>>>(Opart, Mpart, Lpart, attn_o, 16);

  // 7) O projection -> out_f (resid source) + out_b (bf16 for fused-LN GEMM)
  gemm_bf16<<<dim3(6, 8), 256, 0, stream>>>(attn_o, w_cao, ca_ob, nullptr, out_f, out_b,
                                            1024, 768, 768, 0,
                                            nullptr, nullptr, nullptr, nullptr,
                                            nullptr, nullptr, nullptr);
  rowstats_kernel<<<256, 256, 0, stream>>>(out_b, muo, rso);

  // 8) MLP up with fused input-LN(no) + GELU -> g_b
  gemm_bf16<<<dim3(24, 8), 256, 0, stream>>>(out_b, w_m1, nullptr, nullptr, nullptr, g_b,
                                             1024, 3072, 768, 4,
                                             muo, rso, s1m, s2m,
                                             nullptr, nullptr, nullptr);

  // 9) MLP down + residual(out)
  gemm_bf16<<<dim3(6, 8), 256, 0, stream>>>(g_b, w_m2, m2_b, out_f, tok_f, tok_b,
                                            1024, 768, 3072, 0,
                                            nullptr, nullptr, nullptr, nullptr,
                                            nullptr, nullptr, nullptr);

  // 10) merged SA Q/K/V projection -> xqkv [1024][2304]
  gemm_bf16<<<dim3(18, 8), 256, 0, stream>>>(tok_b, w_saq, sab_cat, nullptr, nullptr, xqkv,
                                             1024, 2304, 768, 0,
                                             nullptr, nullptr, nullptr, nullptr,
                                             nullptr, nullptr, nullptr);

  // 11) self-attention
  flash_kernel<<<dim3(4, 8, 4), 256, 0, stream>>>(xqkv, xqkv + 768, xqkv + 1536, sa_o,
                                                  256, 256, 256, 256, 2304);

  // 12) SA O-projection + residual(tok) -> y_f + y_b
  gemm_bf16<<<dim3(6, 8), 256, 0, stream>>>(sa_o, w_sao, sa_ob, tok_f, y_f, y_b,
                                            1024, 768, 768, 0,
                                            nullptr, nullptr, nullptr, nullptr,
                                            nullptr, nullptr, nullptr);
  rowstats_kernel<<<256, 256, 0, stream>>>(y_b, muy, rsy);

  // 13) FF up with fused input-LN(n1) + ReLU -> ff1
  gemm_bf16<<<dim3(12, 8), 256, 0, stream>>>(y_b, w_f1, nullptr, nullptr, nullptr, ff1,
                                             1024, 1536, 768, 5,
                                             muy, rsy, s1f, s2f,
                                             nullptr, nullptr, nullptr);

  // 14) FF down + x1 residual reconstructed from y (act=6) -> z_f
  gemm_bf16<<<dim3(6, 8), 256, 0, stream>>>(ff1, w_f2, f2_b, nullptr, z_f, nullptr,
                                            1024, 768, 1536, 6,
                                            muy, rsy, nullptr, nullptr,
                                            y_f, n1_g, n1_b);

  // 15) LN n2 -> d_out
  ln_kernel<<<1024, 256, 0, stream>>>(z_f, n2_g, n2_b, (float*)d_out);
}

// Round 13
// 685.372 us; speedup vs baseline: 1.0001x; 1.0001x over previous
//
#include <hip/hip_runtime.h>
#include <hip/hip_bf16.h>
#include <math.h>

typedef __hip_bfloat16 bf16;
typedef __attribute__((ext_vector_type(8))) short short8;
typedef __attribute__((ext_vector_type(4))) short short4v;
typedef __attribute__((ext_vector_type(4))) float f32x4;

__device__ __forceinline__ void gload16(const bf16* g, bf16* l) {
  __builtin_amdgcn_global_load_lds((const __attribute__((address_space(1))) void*)(g),
                                   (__attribute__((address_space(3))) void*)(l), 16, 0, 0);
}
__device__ __forceinline__ float bfu2f(unsigned short u) {
  union { unsigned u; float f; } c; c.u = ((unsigned)u) << 16; return c.f;
}
__device__ __forceinline__ short bf2s(float v) {
  union { bf16 h; short s; } c; c.h = __float2bfloat16(v); return c.s;
}
__device__ __forceinline__ short4v packbf4(f32x4 v) {
  short4v o;
  o[0] = bf2s(v[0]); o[1] = bf2s(v[1]); o[2] = bf2s(v[2]); o[3] = bf2s(v[3]);
  return o;
}
__device__ __forceinline__ float geluf(float x) {
  return 0.5f * x * (1.f + tanhf(0.79788456080286535f * (x + 0.044715f * x * x * x)));
}

// ---------------------------------------------------------------------------
// Fused input preprocessing. Block ranges:
//   [0,29952)        prepack: fp32 [rows][sc] -> bf16 [rows][dc] (+opt col scale)
//   [29952,40192)    im2col (K padded to 640, 8 elems/thread)
//   [40192,40960)    s12 ca_kw (nkv): s1v/s2v (768)
//   [40960,41088)    LN(latents) -> q_ln (rows 64..127 zeroed)
//   [41088,41097)    concat3 SA biases -> sab_cat
//   [41097,44169)    s12 m1_w (no):  s1m/s2m (3072)
//   [44169,45705)    s12 f1_w (n1):  s1f/s2f (1536)
// ---------------------------------------------------------------------------
struct Seg { const float* src; bf16* dst; int rows, sc, dc; const float* scale; };
struct Segs { Seg s[13]; };

__global__ __launch_bounds__(256) void preproc_kernel(
    Segs segs,
    const float* __restrict__ frames, bf16* __restrict__ imcol,
    const float* __restrict__ kw, const float* __restrict__ nkv_g,
    const float* __restrict__ nkv_b, const float* __restrict__ kb,
    float* __restrict__ s1, float* __restrict__ s2,
    const float* __restrict__ latents, const float* __restrict__ nq_g,
    const float* __restrict__ nq_b, bf16* __restrict__ q_ln,
    const float* __restrict__ ba, const float* __restrict__ bb,
    const float* __restrict__ bc, float* __restrict__ sab_cat,
    const float* __restrict__ m1w, const float* __restrict__ no_g,
    const float* __restrict__ no_b, const float* __restrict__ m1b,
    float* __restrict__ s1m, float* __restrict__ s2m,
    const float* __restrict__ f1w, const float* __restrict__ n1_g,
    const float* __restrict__ n1_b, const float* __restrict__ f1b,
    float* __restrict__ s1f, float* __restrict__ s2f) {
  __shared__ float red[16];
  int b = blockIdx.x, tid = threadIdx.x;
  if (b < 29952) {
    Seg sg = segs.s[b / 2304];
    int bx = b % 2304;
    long long total = (long long)sg.rows * sg.dc;
    for (long long idx = (long long)bx * 256 + tid; idx < total; idx += 2304LL * 256) {
      int r = (int)(idx / sg.dc), c = (int)(idx % sg.dc);
      float v = (c < sg.sc) ? sg.src[(long long)r * sg.sc + c] : 0.f;
      if (sg.scale && c < sg.sc) v *= sg.scale[c];
      sg.dst[idx] = __float2bfloat16(v);
    }
    return;
  }
  if (b < 40192) {
    unsigned idx8 = (unsigned)(b - 29952) * 256u + tid;  // < 32768*80 exactly
    unsigned m = idx8 / 80u;
    unsigned k0 = (idx8 % 80u) * 8u;
    unsigned n = m >> 8;
    unsigned p = m & 255u;
    unsigned py = p >> 4, px = p & 15u;
    const float* fb = frames + ((size_t)n * 3u) * 224u * 224u +
                      (size_t)py * 14u * 224u + px * 14u;
    short8 o;
    #pragma unroll
    for (int e = 0; e < 8; ++e) {
      unsigned k = k0 + e;
      float v = 0.f;
      if (k < 588u) {
        unsigned c = k / 196u, r = k % 196u;
        unsigned i = r / 14u, j = r % 14u;
        v = fb[((size_t)c * 224u + i) * 224u + j];
      }
      o[e] = bf2s(v);
    }
    *(short8*)(imcol + (size_t)m * 640u + k0) = o;
    return;
  }
  const float* wsrc = nullptr; const float* gv = nullptr; const float* bv = nullptr;
  const float* bias = nullptr; float* o1 = nullptr; float* o2 = nullptr;
  int j = -1;
  if (b < 40960) {
    j = b - 40192; wsrc = kw; gv = nkv_g; bv = nkv_b; bias = kb; o1 = s1; o2 = s2;
  } else if (b < 41088) {
    int row = b - 40960;
    size_t base = (size_t)row * 768;
    if (row >= 64) {
      for (int i = 0; i < 3; ++i) q_ln[base + tid + i * 256] = __float2bfloat16(0.f);
      return;
    }
    float x[3];
    for (int i = 0; i < 3; ++i) x[i] = latents[base + tid + i * 256];
    float s = x[0] + x[1] + x[2];
    float sq = x[0] * x[0] + x[1] * x[1] + x[2] * x[2];
    for (int off = 32; off; off >>= 1) {
      s += __shfl_down(s, off);
      sq += __shfl_down(sq, off);
    }
    int w = tid >> 6;
    if ((tid & 63) == 0) { red[w] = s; red[4 + w] = sq; }
    __syncthreads();
    if (tid == 0) {
      red[0] = red[0] + red[1] + red[2] + red[3];
      red[4] = red[4] + red[5] + red[6] + red[7];
    }
    __syncthreads();
    float mean = red[0] * (1.f / 768.f);
    float var = red[4] * (1.f / 768.f) - mean * mean;
    float rs = rsqrtf(var + 1e-5f);
    for (int i = 0; i < 3; ++i) {
      int c = tid + i * 256;
      q_ln[base + c] = __float2bfloat16((x[i] - mean) * rs * nq_g[c] + nq_b[c]);
    }
    return;
  } else if (b < 41097) {
    int i = (b - 41088) * 256 + tid;
    if (i < 2304)
      sab_cat[i] = i < 768 ? ba[i] : (i < 1536 ? bb[i - 768] : bc[i - 1536]);
    return;
  } else if (b < 44169) {
    j = b - 41097; wsrc = m1w; gv = no_g; bv = no_b; bias = m1b; o1 = s1m; o2 = s2m;
  } else {
    j = b - 44169; wsrc = f1w; gv = n1_g; bv = n1_b; bias = f1b; o1 = s1f; o2 = s2f;
  }
  {
    const float* wr_ = wsrc + (size_t)j * 768;
    float a = 0.f, c = 0.f;
    #pragma unroll
    for (int i = 0; i < 3; ++i) {
      int d = tid + i * 256;
      float wv = wr_[d];
      a += wv * gv[d];
      c += wv * bv[d];
    }
    for (int off = 32; off; off >>= 1) { a += __shfl_down(a, off); c += __shfl_down(c, off); }
    int w = tid >> 6;
    if ((tid & 63) == 0) { red[w] = a; red[8 + w] = c; }
    __syncthreads();
    if (tid == 0) {
      o1[j] = red[0] + red[1] + red[2] + red[3];
      o2[j] = red[8] + red[9] + red[10] + red[11] + bias[j];
    }
  }
}

// per-row mean / rsqrt(var+eps) of bf16 [rows][768]; 1 wave per row
__global__ __launch_bounds__(256) void rowstats_kernel(const bf16* __restrict__ x,
                                                       float* __restrict__ mu,
                                                       float* __restrict__ rs) {
  int row = blockIdx.x * 4 + (threadIdx.x >> 6);
  int lane = threadIdx.x & 63;
  const unsigned short* p = (const unsigned short*)(x + (size_t)row * 768);
  float s = 0.f, sq = 0.f;
  #pragma unroll
  for (int i = 0; i < 3; ++i) {
    ushort4 v = *(const ushort4*)(p + lane * 4 + i * 256);
    float f0 = bfu2f(v.x), f1 = bfu2f(v.y), f2 = bfu2f(v.z), f3 = bfu2f(v.w);
    s += f0 + f1 + f2 + f3;
    sq += f0 * f0 + f1 * f1 + f2 * f2 + f3 * f3;
  }
  for (int off = 32; off; off >>= 1) { s += __shfl_down(s, off); sq += __shfl_down(sq, off); }
  if (lane == 0) {
    float m = s * (1.f / 768.f);
    float var = sq * (1.f / 768.f) - m * m;
    mu[row] = m;
    rs[row] = rsqrtf(var + 1e-5f);
  }
}

// ---------------------------------------------------------------------------
// LayerNorm over D=768 (final n2 only)
// ---------------------------------------------------------------------------
__global__ __launch_bounds__(256) void ln_kernel(const float* __restrict__ inF,
                                                 const float* __restrict__ g,
                                                 const float* __restrict__ b,
                                                 float* __restrict__ outF) {
  int row = blockIdx.x;
  int tid = threadIdx.x;
  __shared__ float red[8];
  size_t base = (size_t)row * 768;
  float x[3];
  for (int i = 0; i < 3; ++i) x[i] = inF[base + tid + i * 256];
  float s = x[0] + x[1] + x[2];
  float sq = x[0] * x[0] + x[1] * x[1] + x[2] * x[2];
  for (int off = 32; off; off >>= 1) {
    s += __shfl_down(s, off);
    sq += __shfl_down(sq, off);
  }
  int w = tid >> 6;
  if ((tid & 63) == 0) { red[w] = s; red[4 + w] = sq; }
  __syncthreads();
  if (tid == 0) {
    red[0] = red[0] + red[1] + red[2] + red[3];
    red[4] = red[4] + red[5] + red[6] + red[7];
  }
  __syncthreads();
  float mean = red[0] * (1.f / 768.f);
  float var = red[4] * (1.f / 768.f) - mean * mean;
  float rs = rsqrtf(var + 1e-5f);
  for (int i = 0; i < 3; ++i) {
    int c = tid + i * 256;
    outF[base + c] = (x[i] - mean) * rs * g[c] + b[c];
  }
}

// ---------------------------------------------------------------------------
// 256x256 bf16 MFMA GEMM — counted-vmcnt phase-split (T3+T4+T5), verified R11.
// act: 0=none, 3=split-KV.
// ---------------------------------------------------------------------------
__global__ __launch_bounds__(512, 2) void gemm256(
    const bf16* __restrict__ A, const bf16* __restrict__ Bw,
    const float* __restrict__ bias,
    bf16* __restrict__ outB,
    int M, int N, int K, int act,
    const float* __restrict__ rowMu, const float* __restrict__ rowRs,
    const float* __restrict__ s1, const float* __restrict__ s2,
    bf16* __restrict__ outB2) {
  __shared__ __align__(16) bf16 As[4][8192];   // 4 x 16KB
  __shared__ __align__(16) bf16 Bs[4][8192];
  int tid = threadIdx.x;
  int nwg = gridDim.x * gridDim.y;
  int orig = blockIdx.y * gridDim.x + blockIdx.x;
  int xcd = orig & 7, loc = orig >> 3;
  int qq = nwg >> 3, rr = nwg & 7;
  int swz = (xcd < rr) ? (xcd * (qq + 1) + loc) : (rr * (qq + 1) + (xcd - rr) * qq + loc);
  int m0 = (swz / gridDim.x) * 256, n0 = (swz % gridDim.x) * 256;

  int lane = tid & 63, w = tid >> 6;      // 8 waves
  int wr = w >> 2, wc = w & 3;            // 2 x 4 wave grid
  int l15 = lane & 15, lq = lane >> 4;

  f32x4 acc[8][4] = {};

  #define STAGEH(buf, kt, part)                                                \
    {                                                                          \
      int koct_ = w >> 1;                                                      \
      int row0_ = (w & 1) * 64 + ((part) & 1) * 128;                           \
      if ((part) < 2)                                                          \
        gload16(A + (size_t)(m0 + row0_ + lane) * K + (kt) + koct_ * 8,        \
                &As[buf][(koct_ * 256 + row0_) * 8]);                          \
      else                                                                     \
        gload16(Bw + (size_t)(n0 + row0_ + lane) * K + (kt) + koct_ * 8,       \
                &Bs[buf][(koct_ * 256 + row0_) * 8]);                          \
    }

  int T = K >> 5;
  #pragma unroll
  for (int p = 0; p < 4; ++p) STAGEH(0, 0, p);
  #pragma unroll
  for (int p = 0; p < 4; ++p) STAGEH(1, 32, p);
  STAGEH(2, 64, 0);
  STAGEH(2, 64, 1);
  asm volatile("s_waitcnt vmcnt(6)" ::: "memory");
  __builtin_amdgcn_s_barrier();

  for (int t = 0; t < T; ++t) {
    int bufc = t & 3, bufn2 = (t + 2) & 3, bufn3 = (t + 3) & 3;
    int kt2 = (t + 2) << 5, kt3 = (t + 3) << 5;
    short8 af[4], bfr[4];
    #pragma unroll
    for (int ni = 0; ni < 4; ++ni)
      bfr[ni] = *(const short8*)(&Bs[bufc][(lq * 256 + wc * 64 + ni * 16 + l15) * 8]);
    #pragma unroll
    for (int mi = 0; mi < 4; ++mi)
      af[mi] = *(const short8*)(&As[bufc][(lq * 256 + wr * 128 + mi * 16 + l15) * 8]);
    if (t + 2 < T) { STAGEH(bufn2, kt2, 2); STAGEH(bufn2, kt2, 3); }
    __builtin_amdgcn_s_barrier();
    asm volatile("" ::: "memory");
    __builtin_amdgcn_s_setprio(1);
    #pragma unroll
    for (int mi = 0; mi < 4; ++mi)
      #pragma unroll
      for (int ni = 0; ni < 4; ++ni)
        acc[mi][ni] = __builtin_amdgcn_mfma_f32_16x16x32_bf16(bfr[ni], af[mi],
                                                              acc[mi][ni], 0, 0, 0);
    __builtin_amdgcn_s_setprio(0);
    asm volatile("" ::: "memory");
    __builtin_amdgcn_s_barrier();
    #pragma unroll
    for (int mi = 0; mi < 4; ++mi)
      af[mi] = *(const short8*)(&As[bufc][(lq * 256 + wr * 128 + 64 + mi * 16 + l15) * 8]);
    if (t + 3 < T) { STAGEH(bufn3, kt3, 0); STAGEH(bufn3, kt3, 1); }
    if (t + 3 < T) {
      asm volatile("s_waitcnt vmcnt(6)" ::: "memory");
    } else if (t + 2 < T) {
      asm volatile("s_waitcnt vmcnt(4)" ::: "memory");
    } else if (t + 1 < T) {
      asm volatile("s_waitcnt vmcnt(0)" ::: "memory");
    }
    __builtin_amdgcn_s_barrier();
    asm volatile("" ::: "memory");
    __builtin_amdgcn_s_setprio(1);
    #pragma unroll
    for (int mi = 0; mi < 4; ++mi)
      #pragma unroll
      for (int ni = 0; ni < 4; ++ni)
        acc[4 + mi][ni] = __builtin_amdgcn_mfma_f32_16x16x32_bf16(bfr[ni], af[mi],
                                                                  acc[4 + mi][ni], 0, 0, 0);
    __builtin_amdgcn_s_setprio(0);
    asm volatile("" ::: "memory");
    __builtin_amdgcn_s_barrier();
  }
  #undef STAGEH

  // ---- staged, coalesced epilogue ----
  bf16* ldsflat = (bf16*)As;
  bf16* ep = ldsflat + w * 1152;
  int rlo = lane >> 3, cg = lane & 7;

  if (act == 3) {
    int c0w = n0 + wc * 64;
    bool isV = (c0w < 768);
    bf16* dst = isV ? outB : outB2;
    int colbase = isV ? c0w : (c0w - 768);
    f32x4 bv[4], a1[4], a2[4];
    #pragma unroll
    for (int ni = 0; ni < 4; ++ni) {
      int cc = colbase + ni * 16 + lq * 4;
      if (isV) bv[ni] = *(const f32x4*)(bias + cc);
      else { a1[ni] = *(const f32x4*)(s1 + cc); a2[ni] = *(const f32x4*)(s2 + cc); }
    }
    #pragma unroll
    for (int mi = 0; mi < 8; ++mi) {
      int roww = m0 + wr * 128 + mi * 16 + l15;
      float rs_ = 0.f, mu_ = 0.f;
      if (!isV) { rs_ = rowRs[roww]; mu_ = rowMu[roww]; }
      #pragma unroll
      for (int ni = 0; ni < 4; ++ni) {
        f32x4 v;
        if (isV) v = acc[mi][ni] + bv[ni];
        else {
          #pragma unroll
          for (int j = 0; j < 4; ++j)
            v[j] = rs_ * (acc[mi][ni][j] - mu_ * a1[ni][j]) + a2[ni][j];
        }
        *(short4v*)(ep + l15 * 72 + ni * 16 + lq * 4) = packbf4(v);
      }
      asm volatile("s_waitcnt lgkmcnt(0)" ::: "memory");
      #pragma unroll
      for (int p = 0; p < 2; ++p) {
        int r = p * 8 + rlo;
        short8 d = *(const short8*)(ep + r * 72 + cg * 8);
        int rg = m0 + wr * 128 + mi * 16 + r;
        *(short8*)(dst + (size_t)rg * 768 + colbase + cg * 8) = d;
      }
      asm volatile("s_waitcnt lgkmcnt(0)" ::: "memory");
    }
    return;
  }

  {
    int c0w = n0 + wc * 64;
    f32x4 bv[4] = {};
    if (bias) {
      #pragma unroll
      for (int ni = 0; ni < 4; ++ni)
        bv[ni] = *(const f32x4*)(bias + c0w + ni * 16 + lq * 4);
    }
    #pragma unroll
    for (int mi = 0; mi < 8; ++mi) {
      #pragma unroll
      for (int ni = 0; ni < 4; ++ni) {
        f32x4 v = acc[mi][ni] + bv[ni];
        *(short4v*)(ep + l15 * 72 + ni * 16 + lq * 4) = packbf4(v);
      }
      asm volatile("s_waitcnt lgkmcnt(0)" ::: "memory");
      #pragma unroll
      for (int p = 0; p < 2; ++p) {
        int r = p * 8 + rlo;
        short8 d = *(const short8*)(ep + r * 72 + cg * 8);
        int rg = m0 + wr * 128 + mi * 16 + r;
        *(short8*)(outB + (size_t)rg * N + c0w + cg * 8) = d;
      }
      asm volatile("s_waitcnt lgkmcnt(0)" ::: "memory");
    }
  }
}

// ---------------------------------------------------------------------------
// 128x128 bf16 MFMA GEMM (small/medium shapes).
// act: 0=none, 1=gelu, 2=relu,
//      4=fused-input-LN + gelu -> outB, 5=fused-input-LN + relu -> outB,
//      6=bias + LN-residual from yraw/gamma/beta -> outF
// ---------------------------------------------------------------------------
__global__ __launch_bounds__(256) void gemm_bf16(
    const bf16* __restrict__ A, const bf16* __restrict__ Bw,
    const float* __restrict__ bias, const float* __restrict__ resid,
    float* __restrict__ outF, bf16* __restrict__ outB,
    int M, int N, int K, int act,
    const float* __restrict__ rowMu, const float* __restrict__ rowRs,
    const float* __restrict__ s1, const float* __restrict__ s2,
    const float* __restrict__ yraw, const float* __restrict__ gamma,
    const float* __restrict__ beta) {
  __shared__ __align__(16) bf16 As[2][4096];
  __shared__ __align__(16) bf16 Bs[2][4096];
  int tid = threadIdx.x;
  int nwg = gridDim.x * gridDim.y;
  int orig = blockIdx.y * gridDim.x + blockIdx.x;
  int xcd = orig & 7, loc = orig >> 3;
  int qq = nwg >> 3, rr = nwg & 7;
  int swz = (xcd < rr) ? (xcd * (qq + 1) + loc) : (rr * (qq + 1) + (xcd - rr) * qq + loc);
  int m0 = (swz / gridDim.x) * 128, n0 = (swz % gridDim.x) * 128;

  int lane = tid & 63, w = tid >> 6;
  int wr = w >> 1, wc = w & 1;
  int l15 = lane & 15, lq = lane >> 4;
  const bf16* Abase = A + (size_t)m0 * K + w * 8;
  const bf16* Bbase = Bw + (size_t)n0 * K + w * 8;
  f32x4 acc[4][4] = {};

  int nt = K >> 5;
  #pragma unroll
  for (int i = 0; i < 2; ++i) {
    int r = i * 64 + lane;
    gload16(Abase + (size_t)r * K, &As[0][(w * 2 + i) * 512]);
    gload16(Bbase + (size_t)r * K, &Bs[0][(w * 2 + i) * 512]);
  }
  for (int t = 0; t < nt; ++t) {
    int cur = t & 1;
    if (t + 1 < nt) {
      int kt = (t + 1) << 5;
      #pragma unroll
      for (int i = 0; i < 2; ++i) {
        int r = i * 64 + lane;
        gload16(Abase + (size_t)r * K + kt, &As[cur ^ 1][(w * 2 + i) * 512]);
        gload16(Bbase + (size_t)r * K + kt, &Bs[cur ^ 1][(w * 2 + i) * 512]);
      }
      asm volatile("s_waitcnt vmcnt(4)" ::: "memory");
    } else {
      asm volatile("s_waitcnt vmcnt(0)" ::: "memory");
    }
    __builtin_amdgcn_s_barrier();
    asm volatile("" ::: "memory");
    const bf16* Ab = &As[cur][lq * 1024];
    const bf16* Bb = &Bs[cur][lq * 1024];
    short8 af[4], bfr[4];
    #pragma unroll
    for (int mi = 0; mi < 4; ++mi)
      af[mi] = *(const short8*)(Ab + (wr * 64 + mi * 16 + l15) * 8);
    #pragma unroll
    for (int ni = 0; ni < 4; ++ni)
      bfr[ni] = *(const short8*)(Bb + (wc * 64 + ni * 16 + l15) * 8);
    __builtin_amdgcn_s_setprio(1);
    #pragma unroll
    for (int mi = 0; mi < 4; ++mi)
      #pragma unroll
      for (int ni = 0; ni < 4; ++ni)
        acc[mi][ni] = __builtin_amdgcn_mfma_f32_16x16x32_bf16(bfr[ni], af[mi],
                                                              acc[mi][ni], 0, 0, 0);
    __builtin_amdgcn_s_setprio(0);
    asm volatile("" ::: "memory");
    __builtin_amdgcn_s_barrier();
  }

  if (act == 4 || act == 5) {
    #pragma unroll
    for (int ni = 0; ni < 4; ++ni) {
      int c0 = n0 + wc * 64 + ni * 16 + lq * 4;
      f32x4 a1 = *(const f32x4*)(s1 + c0);
      f32x4 a2 = *(const f32x4*)(s2 + c0);
      #pragma unroll
      for (int mi = 0; mi < 4; ++mi) {
        int row = m0 + wr * 64 + mi * 16 + l15;
        float rs_ = rowRs[row], mu_ = rowMu[row];
        f32x4 v;
        #pragma unroll
        for (int j = 0; j < 4; ++j) {
          float x = rs_ * (acc[mi][ni][j] - mu_ * a1[j]) + a2[j];
          v[j] = (act == 4) ? geluf(x) : fmaxf(x, 0.f);
        }
        *(short4v*)(outB + (size_t)row * N + c0) = packbf4(v);
      }
    }
    return;
  }
  if (act == 6) {
    #pragma unroll
    for (int ni = 0; ni < 4; ++ni) {
      int c0 = n0 + wc * 64 + ni * 16 + lq * 4;
      f32x4 bv = *(const f32x4*)(bias + c0);
      f32x4 gm = *(const f32x4*)(gamma + c0);
      f32x4 bt = *(const f32x4*)(beta + c0);
      #pragma unroll
      for (int mi = 0; mi < 4; ++mi) {
        int row = m0 + wr * 64 + mi * 16 + l15;
        float rs_ = rowRs[row], mu_ = rowMu[row];
        size_t idx = (size_t)row * N + c0;
        f32x4 yv = *(const f32x4*)(yraw + idx);
        f32x4 v;
        #pragma unroll
        for (int j = 0; j < 4; ++j)
          v[j] = acc[mi][ni][j] + bv[j] + (rs_ * (yv[j] - mu_) * gm[j] + bt[j]);
        *(f32x4*)(outF + idx) = v;
      }
    }
    return;
  }

  #pragma unroll
  for (int ni = 0; ni < 4; ++ni) {
    int c0 = n0 + wc * 64 + ni * 16 + lq * 4;
    f32x4 bv = {};
    if (bias) bv = *(const f32x4*)(bias + c0);
    #pragma unroll
    for (int mi = 0; mi < 4; ++mi) {
      int row = m0 + wr * 64 + mi * 16 + l15;
      f32x4 v = acc[mi][ni] + bv;
      if (act == 1) {
        #pragma unroll
        for (int j = 0; j < 4; ++j) v[j] = geluf(v[j]);
      } else if (act == 2) {
        #pragma unroll
        for (int j = 0; j < 4; ++j) v[j] = fmaxf(v[j], 0.f);
      }
      size_t idx = (size_t)row * N + c0;
      if (resid) v += *(const f32x4*)(resid + idx);
      if (outF) *(f32x4*)(outF + idx) = v;
      if (outB) *(short4v*)(outB + idx) = packbf4(v);
    }
  }
}

// ---------------------------------------------------------------------------
// Flash attention (non-split, used for SA). HD=96, NH=8.
// ---------------------------------------------------------------------------
__global__ __launch_bounds__(256) void flash_kernel(
    const bf16* __restrict__ Q, const bf16* __restrict__ Kp,
    const bf16* __restrict__ V, bf16* __restrict__ O,
    int Lk, int qRPB, int kRPB, int oRPB, int ld) {
  const float scale = 0.10206207261596575f;  // 1/sqrt(96)
  __shared__ bf16 Vt[96 * 72];
  __shared__ bf16 Ps[4 * 16 * 72];
  int tid = threadIdx.x, lane = tid & 63, w = tid >> 6;
  int l15 = lane & 15, lq = lane >> 4;
  int b = blockIdx.z, h = blockIdx.y, qt = blockIdx.x;
  int qbase = b * qRPB + qt * 64 + w * 16;
  int kbase = b * kRPB;
  int obase = b * oRPB + qt * 64 + w * 16;
  int ch = h * 96;

  short8 aQ[3];
  #pragma unroll
  for (int kd = 0; kd < 3; ++kd)
    aQ[kd] = *(const short8*)(Q + (size_t)(qbase + l15) * ld + ch + kd * 32 + lq * 8);

  f32x4 oacc[6] = {};
  float mrun[4] = {-1e30f, -1e30f, -1e30f, -1e30f};
  float lrun[4] = {0.f, 0.f, 0.f, 0.f};

  for (int kc = 0; kc < Lk; kc += 64) {
    for (int u = tid; u < 768; u += 256) {
      int kk = u / 12, dc = u % 12;
      short8 v = *(const short8*)(V + (size_t)(kbase + kc + kk) * ld + ch + dc * 8);
      const bf16* pv = (const bf16*)&v;
      #pragma unroll
      for (int e = 0; e < 8; ++e) Vt[(dc * 8 + e) * 72 + kk] = pv[e];
    }
    __syncthreads();

    f32x4 sacc[4] = {};
    #pragma unroll
    for (int ni = 0; ni < 4; ++ni)
      #pragma unroll
      for (int kd = 0; kd < 3; ++kd) {
        short8 bK = *(const short8*)(Kp + (size_t)(kbase + kc + ni * 16 + l15) * ld +
                                     ch + kd * 32 + lq * 8);
        sacc[ni] = __builtin_amdgcn_mfma_f32_16x16x32_bf16(aQ[kd], bK, sacc[ni], 0, 0, 0);
      }
    #pragma unroll
    for (int ni = 0; ni < 4; ++ni)
      #pragma unroll
      for (int j = 0; j < 4; ++j) sacc[ni][j] *= scale;

    float al[4];
    #pragma unroll
    for (int j = 0; j < 4; ++j) {
      float mx = fmaxf(fmaxf(sacc[0][j], sacc[1][j]), fmaxf(sacc[2][j], sacc[3][j]));
      #pragma unroll
      for (int off = 1; off < 16; off <<= 1) mx = fmaxf(mx, __shfl_xor(mx, off));
      float mnew = fmaxf(mrun[j], mx);
      float alpha = __expf(mrun[j] - mnew);
      float rsum = 0.f;
      #pragma unroll
      for (int ni = 0; ni < 4; ++ni) {
        float p = __expf(sacc[ni][j] - mnew);
        sacc[ni][j] = p;
        rsum += p;
      }
      #pragma unroll
      for (int off = 1; off < 16; off <<= 1) rsum += __shfl_xor(rsum, off);
      lrun[j] = lrun[j] * alpha + rsum;
      mrun[j] = mnew;
      al[j] = alpha;
    }

    #pragma unroll
    for (int ni = 0; ni < 4; ++ni)
      #pragma unroll
      for (int j = 0; j < 4; ++j)
        Ps[(w * 16 + lq * 4 + j) * 72 + ni * 16 + l15] = __float2bfloat16(sacc[ni][j]);
    #pragma unroll
    for (int t = 0; t < 6; ++t)
      #pragma unroll
      for (int j = 0; j < 4; ++j) oacc[t][j] *= al[j];
    short8 aP[2];
    #pragma unroll
    for (int ks = 0; ks < 2; ++ks)
      aP[ks] = *(const short8*)(&Ps[(w * 16 + l15) * 72 + ks * 32 + lq * 8]);
    #pragma unroll
    for (int t = 0; t < 6; ++t)
      #pragma unroll
      for (int ks = 0; ks < 2; ++ks) {
        short8 bV = *(const short8*)(&Vt[(t * 16 + l15) * 72 + ks * 32 + lq * 8]);
        oacc[t] = __builtin_amdgcn_mfma_f32_16x16x32_bf16(aP[ks], bV, oacc[t], 0, 0, 0);
      }
    __syncthreads();
  }

  #pragma unroll
  for (int t = 0; t < 6; ++t)
    #pragma unroll
    for (int j = 0; j < 4; ++j) {
      int row = obase + lq * 4 + j;
      int col = ch + t * 16 + l15;
      O[(size_t)row * 768 + col] = __float2bfloat16(oacc[t][j] / lrun[j]);
    }
}

// ---------------------------------------------------------------------------
// Split-K flash for cross-attention (broadcast latent Q, 64 rows/batch).
// R11-verified: 8 splits, f32 partials.
// ---------------------------------------------------------------------------
__global__ __launch_bounds__(256) void flash_split_kernel(
    const bf16* __restrict__ Q, const bf16* __restrict__ Kp,
    const bf16* __restrict__ V, float* __restrict__ Opart,
    float* __restrict__ Mpart, float* __restrict__ Lpart,
    int splitLen, int kRPB) {
  const float scale = 0.10206207261596575f;
  __shared__ bf16 Vt[96 * 72];
  __shared__ bf16 Ps[4 * 16 * 72];
  int tid = threadIdx.x, lane = tid & 63, w = tid >> 6;
  int l15 = lane & 15, lq = lane >> 4;
  int s = blockIdx.x, h = blockIdx.y, b = blockIdx.z;
  int kbase = b * kRPB + s * splitLen;
  int ch = h * 96;

  short8 aQ[3];
  #pragma unroll
  for (int kd = 0; kd < 3; ++kd)
    aQ[kd] = *(const short8*)(Q + (size_t)(w * 16 + l15) * 768 + ch + kd * 32 + lq * 8);

  f32x4 oacc[6] = {};
  float mrun[4] = {-1e30f, -1e30f, -1e30f, -1e30f};
  float lrun[4] = {0.f, 0.f, 0.f, 0.f};

  for (int kc = 0; kc < splitLen; kc += 64) {
    for (int u = tid; u < 768; u += 256) {
      int kk = u / 12, dc = u % 12;
      short8 v = *(const short8*)(V + (size_t)(kbase + kc + kk) * 768 + ch + dc * 8);
      const bf16* pv = (const bf16*)&v;
      #pragma unroll
      for (int e = 0; e < 8; ++e) Vt[(dc * 8 + e) * 72 + kk] = pv[e];
    }
    __syncthreads();

    f32x4 sacc[4] = {};
    #pragma unroll
    for (int ni = 0; ni < 4; ++ni)
      #pragma unroll
      for (int kd = 0; kd < 3; ++kd) {
        short8 bK = *(const short8*)(Kp + (size_t)(kbase + kc + ni * 16 + l15) * 768 +
                                     ch + kd * 32 + lq * 8);
        sacc[ni] = __builtin_amdgcn_mfma_f32_16x16x32_bf16(aQ[kd], bK, sacc[ni], 0, 0, 0);
      }
    #pragma unroll
    for (int ni = 0; ni < 4; ++ni)
      #pragma unroll
      for (int j = 0; j < 4; ++j) sacc[ni][j] *= scale;

    float al[4];
    #pragma unroll
    for (int j = 0; j < 4; ++j) {
      float mx = fmaxf(fmaxf(sacc[0][j], sacc[1][j]), fmaxf(sacc[2][j], sacc[3][j]));
      #pragma unroll
      for (int off = 1; off < 16; off <<= 1) mx = fmaxf(mx, __shfl_xor(mx, off));
      float mnew = fmaxf(mrun[j], mx);
      float alpha = __expf(mrun[j] - mnew);
      float rsum = 0.f;
      #pragma unroll
      for (int ni = 0; ni < 4; ++ni) {
        float p = __expf(sacc[ni][j] - mnew);
        sacc[ni][j] = p;
        rsum += p;
      }
      #pragma unroll
      for (int off = 1; off < 16; off <<= 1) rsum += __shfl_xor(rsum, off);
      lrun[j] = lrun[j] * alpha + rsum;
      mrun[j] = mnew;
      al[j] = alpha;
    }

    #pragma unroll
    for (int ni = 0; ni < 4; ++ni)
      #pragma unroll
      for (int j = 0; j < 4; ++j)
        Ps[(w * 16 + lq * 4 + j) * 72 + ni * 16 + l15] = __float2bfloat16(sacc[ni][j]);
    #pragma unroll
    for (int t = 0; t < 6; ++t)
      #pragma unroll
      for (int j = 0; j < 4; ++j) oacc[t][j] *= al[j];
    short8 aP[2];
    #pragma unroll
    for (int ks = 0; ks < 2; ++ks)
      aP[ks] = *(const short8*)(&Ps[(w * 16 + l15) * 72 + ks * 32 + lq * 8]);
    #pragma unroll
    for (int t = 0; t < 6; ++t)
      #pragma unroll
      for (int ks = 0; ks < 2; ++ks) {
        short8 bV = *(const short8*)(&Vt[(t * 16 + l15) * 72 + ks * 32 + lq * 8]);
        oacc[t] = __builtin_amdgcn_mfma_f32_16x16x32_bf16(aP[ks], bV, oacc[t], 0, 0, 0);
      }
    __syncthreads();
  }

  int orow = b * 64 + w * 16;
  #pragma unroll
  for (int t = 0; t < 6; ++t)
    #pragma unroll
    for (int j = 0; j < 4; ++j)
      Opart[(size_t)(s * 1024 + orow + lq * 4 + j) * 768 + ch + t * 16 + l15] = oacc[t][j];
  if (l15 == 0) {
    #pragma unroll
    for (int j = 0; j < 4; ++j) {
      int qqi = w * 16 + lq * 4 + j;
      int mi = ((s * 16 + b) * 8 + h) * 64 + qqi;
      Mpart[mi] = mrun[j];
      Lpart[mi] = lrun[j];
    }
  }
}

__global__ __launch_bounds__(256) void flash_merge_kernel(
    const float* __restrict__ Opart, const float* __restrict__ Mpart,
    const float* __restrict__ Lpart, bf16* __restrict__ O, int nsplit) {
  int row = blockIdx.x;   // b*64+q
  int tid = threadIdx.x;
  int c0 = tid * 3;
  int b = row >> 6, q = row & 63;
  int h = c0 / 96;
  float m = -1e30f;
  for (int s = 0; s < nsplit; ++s)
    m = fmaxf(m, Mpart[((s * 16 + b) * 8 + h) * 64 + q]);
  float l = 0.f, o0 = 0.f, o1 = 0.f, o2 = 0.f;
  for (int s = 0; s < nsplit; ++s) {
    int mi = ((s * 16 + b) * 8 + h) * 64 + q;
    float ws = __expf(Mpart[mi] - m);
    l += ws * Lpart[mi];
    const float* op = Opart + (size_t)(s * 1024 + row) * 768 + c0;
    o0 += ws * op[0]; o1 += ws * op[1]; o2 += ws * op[2];
  }
  float inv = 1.f / l;
  size_t ob = (size_t)row * 768 + c0;
  O[ob]     = __float2bfloat16(o0 * inv);
  O[ob + 1] = __float2bfloat16(o1 * inv);
  O[ob + 2] = __float2bfloat16(o2 * inv);
}

// ---------------------------------------------------------------------------
extern "C" void kernel_launch(void* const* d_in, const int* in_sizes, int n_in,
                              void* d_out, int out_size, void* d_ws, size_t ws_size,
                              hipStream_t stream) {
  const float* frames = (const float*)d_in[0];
  const float* pe_w   = (const float*)d_in[1];
  const float* pe_b   = (const float*)d_in[2];
  const float* latents= (const float*)d_in[3];
  const float* ca_qw  = (const float*)d_in[4];  const float* ca_qb = (const float*)d_in[5];
  const float* ca_kw  = (const float*)d_in[6];  const float* ca_kb = (const float*)d_in[7];
  const float* ca_vw  = (const float*)d_in[8];  const float* ca_vb = (const float*)d_in[9];
  const float* ca_ow  = (const float*)d_in[10]; const float* ca_ob = (const float*)d_in[11];
  const float* nq_g   = (const float*)d_in[12]; const float* nq_b  = (const float*)d_in[13];
  const float* nkv_g  = (const float*)d_in[14]; const float* nkv_b = (const float*)d_in[15];
  const float* no_g   = (const float*)d_in[16]; const float* no_b  = (const float*)d_in[17];
  const float* m1_w   = (const float*)d_in[18]; const float* m1_b  = (const float*)d_in[19];
  const float* m2_w   = (const float*)d_in[20]; const float* m2_b  = (const float*)d_in[21];
  const float* sa_qw  = (const float*)d_in[22]; const float* sa_qb = (const float*)d_in[23];
  const float* sa_kw  = (const float*)d_in[24]; const float* sa_kb = (const float*)d_in[25];
  const float* sa_vw  = (const float*)d_in[26]; const float* sa_vb = (const float*)d_in[27];
  const float* sa_ow  = (const float*)d_in[28]; const float* sa_ob = (const float*)d_in[29];
  const float* f1_w   = (const float*)d_in[30]; const float* f1_b  = (const float*)d_in[31];
  const float* f2_w   = (const float*)d_in[32]; const float* f2_b  = (const float*)d_in[33];
  const float* n1_g   = (const float*)d_in[34]; const float* n1_b  = (const float*)d_in[35];
  const float* n2_g   = (const float*)d_in[36]; const float* n2_b  = (const float*)d_in[37];

  char* ws = (char*)d_ws;
  size_t off = 0;
  auto take = [&](size_t bytes) -> char* {
    char* p = ws + off;
    off += (bytes + 255) & ~(size_t)255;
    return p;
  };

  // persistent bf16 weights
  bf16* w_pe   = (bf16*)take((size_t)768 * 640 * 2);
  bf16* w_caq  = (bf16*)take((size_t)768 * 768 * 2);
  bf16* w_cakv = (bf16*)take((size_t)1536 * 768 * 2);  // [V(768); K'(768)] rows
  bf16* w_cao  = (bf16*)take((size_t)768 * 768 * 2);
  bf16* w_m1   = (bf16*)take((size_t)3072 * 768 * 2);  // scaled by no_g
  bf16* w_m2   = (bf16*)take((size_t)768 * 3072 * 2);
  bf16* w_saq  = (bf16*)take((size_t)768 * 768 * 2);   // contiguous with sak/sav
  bf16* w_sak  = (bf16*)take((size_t)768 * 768 * 2);
  bf16* w_sav  = (bf16*)take((size_t)768 * 768 * 2);
  bf16* w_sao  = (bf16*)take((size_t)768 * 768 * 2);
  bf16* w_f1   = (bf16*)take((size_t)1536 * 768 * 2);  // scaled by n1_g
  bf16* w_f2   = (bf16*)take((size_t)768 * 1536 * 2);
  float* sab_cat = (float*)take((size_t)2304 * 4);
  float* s1v  = (float*)take((size_t)768 * 4);
  float* s2v  = (float*)take((size_t)768 * 4);
  float* s1m  = (float*)take((size_t)3072 * 4);
  float* s2m  = (float*)take((size_t)3072 * 4);
  float* s1f  = (float*)take((size_t)1536 * 4);
  float* s2f  = (float*)take((size_t)1536 * 4);
  float* muv  = (float*)take((size_t)32768 * 4);
  float* rsv  = (float*)take((size_t)32768 * 4);
  float* muo  = (float*)take((size_t)1024 * 4);
  float* rso  = (float*)take((size_t)1024 * 4);
  float* muy  = (float*)take((size_t)1024 * 4);
  float* rsy  = (float*)take((size_t)1024 * 4);

  bf16* q_ln = (bf16*)take((size_t)128 * 768 * 2);
  bf16* qh   = (bf16*)take((size_t)128 * 768 * 2);

  bf16* kv   = (bf16*)take((size_t)32768 * 768 * 2);   // raw patch tokens
  bf16* vhkh = (bf16*)take((size_t)2 * 32768 * 768 * 2);
  bf16* vh = vhkh;
  bf16* kh = vhkh + (size_t)32768 * 768;
  bf16* imcol = vhkh;  // dead after patch GEMM, before vh/kh are written

  // union region: CA split partials (8 x f32) / stage-2/3 activations
  const size_t REGION = (size_t)32768 * 608 * 2;  // 39,845,888
  char* region = take(REGION);
  float* Opart = (float*)region;                          // 25,165,824 B
  float* Mpart = (float*)(region + 25165824);             //    262,144 B
  float* Lpart = (float*)(region + 25165824 + 262144);    //    262,144 B
  bf16*  attn_o = (bf16*)(region + REGION - (size_t)1024 * 768 * 2);
  size_t ro = 0;
  auto rtake = [&](size_t bytes) -> char* {
    char* p = region + ro;
    ro += (bytes + 255) & ~(size_t)255;
    return p;
  };
  float* out_f  = (float*)rtake((size_t)1024 * 768 * 4);
  bf16*  out_b  = (bf16*)rtake((size_t)1024 * 768 * 2);
  bf16*  g_b    = (bf16*)rtake((size_t)1024 * 3072 * 2);
  float* tok_f  = (float*)rtake((size_t)1024 * 768 * 4);
  bf16*  tok_b  = (bf16*)rtake((size_t)1024 * 768 * 2);
  bf16*  xqkv   = (bf16*)rtake((size_t)1024 * 2304 * 2);
  bf16*  sa_o   = (bf16*)rtake((size_t)1024 * 768 * 2);
  float* y_f    = (float*)rtake((size_t)1024 * 768 * 4);
  bf16*  y_b    = (bf16*)rtake((size_t)1024 * 768 * 2);
  bf16*  ff1    = (bf16*)rtake((size_t)1024 * 1536 * 2);
  float* z_f    = (float*)rtake((size_t)1024 * 768 * 4);
  (void)ws_size; (void)in_sizes; (void)n_in; (void)out_size;

  // 1) fused preprocessing
  Segs segs;
  segs.s[0]  = {pe_w,  w_pe,  768, 588, 640, nullptr};
  segs.s[1]  = {ca_qw, w_caq, 768, 768, 768, nullptr};
  segs.s[2]  = {ca_vw, w_cakv, 768, 768, 768, nullptr};
  segs.s[3]  = {ca_kw, w_cakv + (size_t)768 * 768, 768, 768, 768, nkv_g};
  segs.s[4]  = {ca_ow, w_cao, 768, 768, 768, nullptr};
  segs.s[5]  = {m1_w,  w_m1,  3072, 768, 768, no_g};
  segs.s[6]  = {m2_w,  w_m2,  768, 3072, 3072, nullptr};
  segs.s[7]  = {sa_qw, w_saq, 768, 768, 768, nullptr};
  segs.s[8]  = {sa_kw, w_sak, 768, 768, 768, nullptr};
  segs.s[9]  = {sa_vw, w_sav, 768, 768, 768, nullptr};
  segs.s[10] = {f1_w,  w_f1,  1536, 768, 768, n1_g};
  segs.s[11] = {f2_w,  w_f2,  768, 1536, 1536, nullptr};
  segs.s[12] = {sa_ow, w_sao, 768, 768, 768, nullptr};
  preproc_kernel<<<45705, 256, 0, stream>>>(
      segs, frames, imcol,
      ca_kw, nkv_g, nkv_b, ca_kb, s1v, s2v,
      latents, nq_g, nq_b, q_ln,
      sa_qb, sa_kb, sa_vb, sab_cat,
      m1_w, no_g, no_b, m1_b, s1m, s2m,
      f1_w, n1_g, n1_b, f1_b, s1f, s2f);

  // 2) patch-embed GEMM (256^2, phase-split) -> kv
  gemm256<<<dim3(3, 128), 512, 0, stream>>>(imcol, w_pe, pe_b, kv,
                                            32768, 768, 640, 0,
                                            nullptr, nullptr, nullptr, nullptr, nullptr);

  // 3) Q projection (small)
  gemm_bf16<<<dim3(6, 1), 256, 0, stream>>>(q_ln, w_caq, ca_qb, nullptr, nullptr, qh,
                                            128, 768, 768, 0,
                                            nullptr, nullptr, nullptr, nullptr,
                                            nullptr, nullptr, nullptr);

  // 4) per-row LN stats of kv
  rowstats_kernel<<<8192, 256, 0, stream>>>(kv, muv, rsv);

  // 5) merged V + fused-LN-K projection (256^2, phase-split) -> vh, kh
  gemm256<<<dim3(6, 128), 512, 0, stream>>>(kv, w_cakv, ca_vb, vh,
                                            32768, 1536, 768, 3,
                                            muv, rsv, s1v, s2v, kh);

  // 6) cross-attention split-K: 8 splits x 8 heads x 16 batches (R11 config)
  flash_split_kernel<<<dim3(8, 8, 16), 256, 0, stream>>>(qh, kh, vh, Opart, Mpart, Lpart,
                                                         256, 2048);
  flash_merge_kernel<<<1024, 256, 0, stream>>>(Opart, Mpart, Lpart, attn_o, 8);

  // 7) O projection -> out_f (resid source) + out_b (bf16 for fused-LN GEMM)
  gemm_bf16<<<dim3(6, 8), 256, 0, stream>>>(attn_o, w_cao, ca_ob, nullptr, out_f, out_b,
                                            1024, 768, 768, 0,
                                            nullptr, nullptr, nullptr, nullptr,
                                            nullptr, nullptr, nullptr);
  rowstats_kernel<<<256, 256, 0, stream>>>(out_b, muo, rso);

  // 8) MLP up with fused input-LN(no) + GELU -> g_b
  gemm_bf16<<<dim3(24, 8), 256, 0, stream>>>(out_b, w_m1, nullptr, nullptr, nullptr, g_b,
                                             1024, 3072, 768, 4,
                                             muo, rso, s1m, s2m,
                                             nullptr, nullptr, nullptr);

  // 9) MLP down + residual(out)
  gemm_bf16<<<dim3(6, 8), 256, 0, stream>>>(g_b, w_m2, m2_b, out_f, tok_f, tok_b,
                                            1024, 768, 3072, 0,
                                            nullptr, nullptr, nullptr, nullptr,
                                            nullptr, nullptr, nullptr);

  // 10) merged SA Q/K/V projection -> xqkv [1024][2304]
  gemm_bf16<<<dim3(18, 8), 256, 0, stream>>>(tok_b, w_saq, sab_cat, nullptr, nullptr, xqkv,
                                             1024, 2304, 768, 0,
                                             nullptr, nullptr, nullptr, nullptr,
                                             nullptr, nullptr, nullptr);

  // 11) self-attention
  flash_kernel<<<dim3(4, 8, 4), 256, 0, stream>>>(xqkv, xqkv + 768, xqkv + 1536, sa_o,
                                                  256, 256, 256, 256, 2304);

  // 12) SA O-projection + residual(tok) -> y_f + y_b
  gemm_bf16<<<dim3(6, 8), 256, 0, stream>>>(sa_o, w_sao, sa_ob, tok_f, y_f, y_b,
                                            1024, 768, 768, 0,
                                            nullptr, nullptr, nullptr, nullptr,
                                            nullptr, nullptr, nullptr);
  rowstats_kernel<<<256, 256, 0, stream>>>(y_b, muy, rsy);

  // 13) FF up with fused input-LN(n1) + ReLU -> ff1
  gemm_bf16<<<dim3(12, 8), 256, 0, stream>>>(y_b, w_f1, nullptr, nullptr, nullptr, ff1,
                                             1024, 1536, 768, 5,
                                             muy, rsy, s1f, s2f,
                                             nullptr, nullptr, nullptr);

  // 14) FF down + x1 residual reconstructed from y (act=6) -> z_f
  gemm_bf16<<<dim3(6, 8), 256, 0, stream>>>(ff1, w_f2, f2_b, nullptr, z_f, nullptr,
                                            1024, 768, 1536, 6,
                                            muy, rsy, nullptr, nullptr,
                                            y_f, n1_g, n1_b);

  // 15) LN n2 -> d_out
  ln_kernel<<<1024, 256, 0, stream>>>(z_f, n2_g, n2_b, (float*)d_out);
}

// Round 14
// 672.401 us; speedup vs baseline: 1.0194x; 1.0193x over previous
//
#include <hip/hip_runtime.h>
#include <hip/hip_bf16.h>
#include <math.h>

typedef __hip_bfloat16 bf16;
typedef __attribute__((ext_vector_type(8))) short short8;
typedef __attribute__((ext_vector_type(4))) short short4v;
typedef __attribute__((ext_vector_type(4))) float f32x4;

__device__ __forceinline__ void gload16(const bf16* g, bf16* l) {
  __builtin_amdgcn_global_load_lds((const __attribute__((address_space(1))) void*)(g),
                                   (__attribute__((address_space(3))) void*)(l), 16, 0, 0);
}
__device__ __forceinline__ float bfu2f(unsigned short u) {
  union { unsigned u; float f; } c; c.u = ((unsigned)u) << 16; return c.f;
}
__device__ __forceinline__ short bf2s(float v) {
  union { bf16 h; short s; } c; c.h = __float2bfloat16(v); return c.s;
}
__device__ __forceinline__ short4v packbf4(f32x4 v) {
  short4v o;
  o[0] = bf2s(v[0]); o[1] = bf2s(v[1]); o[2] = bf2s(v[2]); o[3] = bf2s(v[3]);
  return o;
}

// ---------------------------------------------------------------------------
// Fused input preprocessing. Block ranges:
//   [0,29952)       prepack: fp32 [rows][sc] -> bf16 [rows][dc] (+opt col scale)
//   [29952,40192)   im2col (K padded to 640, 8 elems/thread)
//   [40192,40960)   s12: s1[j]=sum g*Wk[j], s2[j]=sum b*Wk[j]+kb[j]
//   [40960,41088)   LN(latents) -> q_ln (rows 64..127 zeroed)
//   [41088,41097)   concat3 SA biases -> sab_cat
// ---------------------------------------------------------------------------
struct Seg { const float* src; bf16* dst; int rows, sc, dc; const float* scale; };
struct Segs { Seg s[13]; };

__global__ __launch_bounds__(256) void preproc_kernel(
    Segs segs,
    const float* __restrict__ frames, bf16* __restrict__ imcol,
    const float* __restrict__ kw, const float* __restrict__ nkv_g,
    const float* __restrict__ nkv_b, const float* __restrict__ kb,
    float* __restrict__ s1, float* __restrict__ s2,
    const float* __restrict__ latents, const float* __restrict__ nq_g,
    const float* __restrict__ nq_b, bf16* __restrict__ q_ln,
    const float* __restrict__ ba, const float* __restrict__ bb,
    const float* __restrict__ bc, float* __restrict__ sab_cat) {
  __shared__ float red[16];
  int b = blockIdx.x, tid = threadIdx.x;
  if (b < 29952) {
    Seg sg = segs.s[b / 2304];
    int bx = b % 2304;
    long long total = (long long)sg.rows * sg.dc;
    for (long long idx = (long long)bx * 256 + tid; idx < total; idx += 2304LL * 256) {
      int r = (int)(idx / sg.dc), c = (int)(idx % sg.dc);
      float v = (c < sg.sc) ? sg.src[(long long)r * sg.sc + c] : 0.f;
      if (sg.scale && c < sg.sc) v *= sg.scale[c];
      sg.dst[idx] = __float2bfloat16(v);
    }
  } else if (b < 40192) {
    unsigned idx8 = (unsigned)(b - 29952) * 256u + tid;  // < 32768*80 exactly
    unsigned m = idx8 / 80u;
    unsigned k0 = (idx8 % 80u) * 8u;
    unsigned n = m >> 8;
    unsigned p = m & 255u;
    unsigned py = p >> 4, px = p & 15u;
    const float* fb = frames + ((size_t)n * 3u) * 224u * 224u +
                      (size_t)py * 14u * 224u + px * 14u;
    short8 o;
    #pragma unroll
    for (int e = 0; e < 8; ++e) {
      unsigned k = k0 + e;
      float v = 0.f;
      if (k < 588u) {
        unsigned c = k / 196u, r = k % 196u;
        unsigned i = r / 14u, j = r % 14u;
        v = fb[((size_t)c * 224u + i) * 224u + j];
      }
      o[e] = bf2s(v);
    }
    *(short8*)(imcol + (size_t)m * 640u + k0) = o;
  } else if (b < 40960) {
    int j = b - 40192;
    const float* wr_ = kw + (size_t)j * 768;
    float a = 0.f, c = 0.f;
    #pragma unroll
    for (int i = 0; i < 3; ++i) {
      int d = tid + i * 256;
      float wv = wr_[d];
      a += wv * nkv_g[d];
      c += wv * nkv_b[d];
    }
    for (int off = 32; off; off >>= 1) { a += __shfl_down(a, off); c += __shfl_down(c, off); }
    int w = tid >> 6;
    if ((tid & 63) == 0) { red[w] = a; red[8 + w] = c; }
    __syncthreads();
    if (tid == 0) {
      s1[j] = red[0] + red[1] + red[2] + red[3];
      s2[j] = red[8] + red[9] + red[10] + red[11] + kb[j];
    }
  } else if (b < 41088) {
    int row = b - 40960;
    size_t base = (size_t)row * 768;
    if (row >= 64) {
      for (int i = 0; i < 3; ++i) q_ln[base + tid + i * 256] = __float2bfloat16(0.f);
      return;
    }
    float x[3];
    for (int i = 0; i < 3; ++i) x[i] = latents[base + tid + i * 256];
    float s = x[0] + x[1] + x[2];
    float sq = x[0] * x[0] + x[1] * x[1] + x[2] * x[2];
    for (int off = 32; off; off >>= 1) {
      s += __shfl_down(s, off);
      sq += __shfl_down(sq, off);
    }
    int w = tid >> 6;
    if ((tid & 63) == 0) { red[w] = s; red[4 + w] = sq; }
    __syncthreads();
    if (tid == 0) {
      red[0] = red[0] + red[1] + red[2] + red[3];
      red[4] = red[4] + red[5] + red[6] + red[7];
    }
    __syncthreads();
    float mean = red[0] * (1.f / 768.f);
    float var = red[4] * (1.f / 768.f) - mean * mean;
    float rs = rsqrtf(var + 1e-5f);
    for (int i = 0; i < 3; ++i) {
      int c = tid + i * 256;
      q_ln[base + c] = __float2bfloat16((x[i] - mean) * rs * nq_g[c] + nq_b[c]);
    }
  } else {
    int i = (b - 41088) * 256 + tid;
    if (i < 2304)
      sab_cat[i] = i < 768 ? ba[i] : (i < 1536 ? bb[i - 768] : bc[i - 1536]);
  }
}

// per-row mean / rsqrt(var+eps) of bf16 [rows][768]; 1 wave per row
__global__ __launch_bounds__(256) void rowstats_kernel(const bf16* __restrict__ x,
                                                       float* __restrict__ mu,
                                                       float* __restrict__ rs) {
  int row = blockIdx.x * 4 + (threadIdx.x >> 6);
  int lane = threadIdx.x & 63;
  const unsigned short* p = (const unsigned short*)(x + (size_t)row * 768);
  float s = 0.f, sq = 0.f;
  #pragma unroll
  for (int i = 0; i < 3; ++i) {
    ushort4 v = *(const ushort4*)(p + lane * 4 + i * 256);
    float f0 = bfu2f(v.x), f1 = bfu2f(v.y), f2 = bfu2f(v.z), f3 = bfu2f(v.w);
    s += f0 + f1 + f2 + f3;
    sq += f0 * f0 + f1 * f1 + f2 * f2 + f3 * f3;
  }
  for (int off = 32; off; off >>= 1) { s += __shfl_down(s, off); sq += __shfl_down(sq, off); }
  if (lane == 0) {
    float m = s * (1.f / 768.f);
    float var = sq * (1.f / 768.f) - m * m;
    mu[row] = m;
    rs[row] = rsqrtf(var + 1e-5f);
  }
}

// ---------------------------------------------------------------------------
// LayerNorm over D=768 (small-row uses)
// ---------------------------------------------------------------------------
__global__ __launch_bounds__(256) void ln_kernel(const float* __restrict__ inF,
                                                 const bf16* __restrict__ inB,
                                                 const float* __restrict__ g,
                                                 const float* __restrict__ b,
                                                 float* __restrict__ outF,
                                                 bf16* __restrict__ outB,
                                                 int validRows) {
  int row = blockIdx.x;
  int tid = threadIdx.x;
  __shared__ float red[8];
  size_t base = (size_t)row * 768;
  if (row >= validRows) {
    for (int i = 0; i < 3; ++i) {
      int c = tid + i * 256;
      if (outB) outB[base + c] = __float2bfloat16(0.f);
      if (outF) outF[base + c] = 0.f;
    }
    return;
  }
  float x[3];
  for (int i = 0; i < 3; ++i) {
    int c = tid + i * 256;
    x[i] = inF ? inF[base + c] : __bfloat162float(inB[base + c]);
  }
  float s = x[0] + x[1] + x[2];
  float sq = x[0] * x[0] + x[1] * x[1] + x[2] * x[2];
  for (int off = 32; off; off >>= 1) {
    s += __shfl_down(s, off);
    sq += __shfl_down(sq, off);
  }
  int w = tid >> 6;
  if ((tid & 63) == 0) { red[w] = s; red[4 + w] = sq; }
  __syncthreads();
  if (tid == 0) {
    red[0] = red[0] + red[1] + red[2] + red[3];
    red[4] = red[4] + red[5] + red[6] + red[7];
  }
  __syncthreads();
  float mean = red[0] * (1.f / 768.f);
  float var = red[4] * (1.f / 768.f) - mean * mean;
  float rs = rsqrtf(var + 1e-5f);
  for (int i = 0; i < 3; ++i) {
    int c = tid + i * 256;
    float y = (x[i] - mean) * rs * g[c] + b[c];
    if (outF) outF[base + c] = y;
    if (outB) outB[base + c] = __float2bfloat16(y);
  }
}

// ---------------------------------------------------------------------------
// 256x256 bf16 MFMA GEMM — counted-vmcnt phase-split schedule (T3+T4+T5):
// BK=32, 4 LDS buffers (128KB), buf = t&3, 2 phases/tile of 16 MFMA each.
// Half-tile staging (128 rows x 32K, 1 gload/thread), 2 halves/phase,
// lead = 10 halves. vmcnt(6) ONCE per tile (tail: 6 -> 4 -> 0).
// Verified R11: KV GEMM 143 -> 122 us.
// act: 0=none, 3=split-KV (cols<768 -> outB+bias; cols>=768 -> outB2 with
// fused-LN epilogue rs*(y-mu*s1)+s2).  M%256==0, N%256==0, K%32==0, K>=96.
// ---------------------------------------------------------------------------
__global__ __launch_bounds__(512, 2) void gemm256(
    const bf16* __restrict__ A, const bf16* __restrict__ Bw,
    const float* __restrict__ bias,
    bf16* __restrict__ outB,
    int M, int N, int K, int act,
    const float* __restrict__ rowMu, const float* __restrict__ rowRs,
    const float* __restrict__ s1, const float* __restrict__ s2,
    bf16* __restrict__ outB2) {
  __shared__ __align__(16) bf16 As[4][8192];   // 4 x 16KB
  __shared__ __align__(16) bf16 Bs[4][8192];
  int tid = threadIdx.x;
  int nwg = gridDim.x * gridDim.y;
  int orig = blockIdx.y * gridDim.x + blockIdx.x;
  int xcd = orig & 7, loc = orig >> 3;
  int qq = nwg >> 3, rr = nwg & 7;
  int swz = (xcd < rr) ? (xcd * (qq + 1) + loc) : (rr * (qq + 1) + (xcd - rr) * qq + loc);
  int m0 = (swz / gridDim.x) * 256, n0 = (swz % gridDim.x) * 256;

  int lane = tid & 63, w = tid >> 6;      // 8 waves
  int wr = w >> 2, wc = w & 3;            // 2 x 4 wave grid
  int l15 = lane & 15, lq = lane >> 4;

  f32x4 acc[8][4] = {};

  #define STAGEH(buf, kt, part)                                                \
    {                                                                          \
      int koct_ = w >> 1;                                                      \
      int row0_ = (w & 1) * 64 + ((part) & 1) * 128;                           \
      if ((part) < 2)                                                          \
        gload16(A + (size_t)(m0 + row0_ + lane) * K + (kt) + koct_ * 8,        \
                &As[buf][(koct_ * 256 + row0_) * 8]);                          \
      else                                                                     \
        gload16(Bw + (size_t)(n0 + row0_ + lane) * K + (kt) + koct_ * 8,       \
                &Bs[buf][(koct_ * 256 + row0_) * 8]);                          \
    }

  int T = K >> 5;                          // requires T >= 3 (K=640/768 ok)
  #pragma unroll
  for (int p = 0; p < 4; ++p) STAGEH(0, 0, p);
  #pragma unroll
  for (int p = 0; p < 4; ++p) STAGEH(1, 32, p);
  STAGEH(2, 64, 0);
  STAGEH(2, 64, 1);
  asm volatile("s_waitcnt vmcnt(6)" ::: "memory");
  __builtin_amdgcn_s_barrier();

  for (int t = 0; t < T; ++t) {
    int bufc = t & 3, bufn2 = (t + 2) & 3, bufn3 = (t + 3) & 3;
    int kt2 = (t + 2) << 5, kt3 = (t + 3) << 5;
    short8 af[4], bfr[4];
    // ---- phase q=0: B frags (whole tile) + A rows 0..63 of wave's half ----
    #pragma unroll
    for (int ni = 0; ni < 4; ++ni)
      bfr[ni] = *(const short8*)(&Bs[bufc][(lq * 256 + wc * 64 + ni * 16 + l15) * 8]);
    #pragma unroll
    for (int mi = 0; mi < 4; ++mi)
      af[mi] = *(const short8*)(&As[bufc][(lq * 256 + wr * 128 + mi * 16 + l15) * 8]);
    if (t + 2 < T) { STAGEH(bufn2, kt2, 2); STAGEH(bufn2, kt2, 3); }
    __builtin_amdgcn_s_barrier();
    asm volatile("" ::: "memory");
    __builtin_amdgcn_s_setprio(1);
    #pragma unroll
    for (int mi = 0; mi < 4; ++mi)
      #pragma unroll
      for (int ni = 0; ni < 4; ++ni)
        acc[mi][ni] = __builtin_amdgcn_mfma_f32_16x16x32_bf16(bfr[ni], af[mi],
                                                              acc[mi][ni], 0, 0, 0);
    __builtin_amdgcn_s_setprio(0);
    asm volatile("" ::: "memory");
    __builtin_amdgcn_s_barrier();
    // ---- phase q=1: A rows 64..127 of wave's half; counted tile wait ----
    #pragma unroll
    for (int mi = 0; mi < 4; ++mi)
      af[mi] = *(const short8*)(&As[bufc][(lq * 256 + wr * 128 + 64 + mi * 16 + l15) * 8]);
    if (t + 3 < T) { STAGEH(bufn3, kt3, 0); STAGEH(bufn3, kt3, 1); }
    if (t + 3 < T) {
      asm volatile("s_waitcnt vmcnt(6)" ::: "memory");
    } else if (t + 2 < T) {
      asm volatile("s_waitcnt vmcnt(4)" ::: "memory");
    } else if (t + 1 < T) {
      asm volatile("s_waitcnt vmcnt(0)" ::: "memory");
    }
    __builtin_amdgcn_s_barrier();
    asm volatile("" ::: "memory");
    __builtin_amdgcn_s_setprio(1);
    #pragma unroll
    for (int mi = 0; mi < 4; ++mi)
      #pragma unroll
      for (int ni = 0; ni < 4; ++ni)
        acc[4 + mi][ni] = __builtin_amdgcn_mfma_f32_16x16x32_bf16(bfr[ni], af[mi],
                                                                  acc[4 + mi][ni], 0, 0, 0);
    __builtin_amdgcn_s_setprio(0);
    asm volatile("" ::: "memory");
    __builtin_amdgcn_s_barrier();
  }
  #undef STAGEH

  // ---- staged, coalesced epilogue ----
  // wave-private LDS region: 16 rows x 72 elems bf16 (144B rows, 16B-aligned)
  bf16* ldsflat = (bf16*)As;
  bf16* ep = ldsflat + w * 1152;
  int rlo = lane >> 3, cg = lane & 7;

  if (act == 3) {
    int c0w = n0 + wc * 64;                 // wave-uniform; 64-aligned
    bool isV = (c0w < 768);
    bf16* dst = isV ? outB : outB2;
    int colbase = isV ? c0w : (c0w - 768);
    f32x4 bv[4], a1[4], a2[4];
    #pragma unroll
    for (int ni = 0; ni < 4; ++ni) {
      int cc = colbase + ni * 16 + lq * 4;
      if (isV) bv[ni] = *(const f32x4*)(bias + cc);
      else { a1[ni] = *(const f32x4*)(s1 + cc); a2[ni] = *(const f32x4*)(s2 + cc); }
    }
    #pragma unroll
    for (int mi = 0; mi < 8; ++mi) {
      int roww = m0 + wr * 128 + mi * 16 + l15;
      float rs_ = 0.f, mu_ = 0.f;
      if (!isV) { rs_ = rowRs[roww]; mu_ = rowMu[roww]; }
      #pragma unroll
      for (int ni = 0; ni < 4; ++ni) {
        f32x4 v;
        if (isV) v = acc[mi][ni] + bv[ni];
        else {
          #pragma unroll
          for (int j = 0; j < 4; ++j)
            v[j] = rs_ * (acc[mi][ni][j] - mu_ * a1[ni][j]) + a2[ni][j];
        }
        *(short4v*)(ep + l15 * 72 + ni * 16 + lq * 4) = packbf4(v);
      }
      asm volatile("s_waitcnt lgkmcnt(0)" ::: "memory");
      #pragma unroll
      for (int p = 0; p < 2; ++p) {
        int r = p * 8 + rlo;
        short8 d = *(const short8*)(ep + r * 72 + cg * 8);
        int rg = m0 + wr * 128 + mi * 16 + r;
        *(short8*)(dst + (size_t)rg * 768 + colbase + cg * 8) = d;
      }
      asm volatile("s_waitcnt lgkmcnt(0)" ::: "memory");
    }
    return;
  }

  {
    int c0w = n0 + wc * 64;
    f32x4 bv[4] = {};
    if (bias) {
      #pragma unroll
      for (int ni = 0; ni < 4; ++ni)
        bv[ni] = *(const f32x4*)(bias + c0w + ni * 16 + lq * 4);
    }
    #pragma unroll
    for (int mi = 0; mi < 8; ++mi) {
      #pragma unroll
      for (int ni = 0; ni < 4; ++ni) {
        f32x4 v = acc[mi][ni] + bv[ni];
        *(short4v*)(ep + l15 * 72 + ni * 16 + lq * 4) = packbf4(v);
      }
      asm volatile("s_waitcnt lgkmcnt(0)" ::: "memory");
      #pragma unroll
      for (int p = 0; p < 2; ++p) {
        int r = p * 8 + rlo;
        short8 d = *(const short8*)(ep + r * 72 + cg * 8);
        int rg = m0 + wr * 128 + mi * 16 + r;
        *(short8*)(outB + (size_t)rg * N + c0w + cg * 8) = d;
      }
      asm volatile("s_waitcnt lgkmcnt(0)" ::: "memory");
    }
  }
}

// ---------------------------------------------------------------------------
// 128x128 bf16 MFMA GEMM (small/medium shapes).
// act: 0=none, 1=gelu(tanh), 2=relu.
// ---------------------------------------------------------------------------
__global__ __launch_bounds__(256) void gemm_bf16(
    const bf16* __restrict__ A, const bf16* __restrict__ Bw,
    const float* __restrict__ bias, const float* __restrict__ resid,
    float* __restrict__ outF, bf16* __restrict__ outB,
    int M, int N, int K, int act) {
  __shared__ __align__(16) bf16 As[2][4096];
  __shared__ __align__(16) bf16 Bs[2][4096];
  int tid = threadIdx.x;
  int nwg = gridDim.x * gridDim.y;
  int orig = blockIdx.y * gridDim.x + blockIdx.x;
  int xcd = orig & 7, loc = orig >> 3;
  int qq = nwg >> 3, rr = nwg & 7;
  int swz = (xcd < rr) ? (xcd * (qq + 1) + loc) : (rr * (qq + 1) + (xcd - rr) * qq + loc);
  int m0 = (swz / gridDim.x) * 128, n0 = (swz % gridDim.x) * 128;

  int lane = tid & 63, w = tid >> 6;
  int wr = w >> 1, wc = w & 1;
  int l15 = lane & 15, lq = lane >> 4;
  const bf16* Abase = A + (size_t)m0 * K + w * 8;
  const bf16* Bbase = Bw + (size_t)n0 * K + w * 8;
  f32x4 acc[4][4] = {};

  int nt = K >> 5;
  #pragma unroll
  for (int i = 0; i < 2; ++i) {
    int r = i * 64 + lane;
    gload16(Abase + (size_t)r * K, &As[0][(w * 2 + i) * 512]);
    gload16(Bbase + (size_t)r * K, &Bs[0][(w * 2 + i) * 512]);
  }
  for (int t = 0; t < nt; ++t) {
    int cur = t & 1;
    if (t + 1 < nt) {
      int kt = (t + 1) << 5;
      #pragma unroll
      for (int i = 0; i < 2; ++i) {
        int r = i * 64 + lane;
        gload16(Abase + (size_t)r * K + kt, &As[cur ^ 1][(w * 2 + i) * 512]);
        gload16(Bbase + (size_t)r * K + kt, &Bs[cur ^ 1][(w * 2 + i) * 512]);
      }
      asm volatile("s_waitcnt vmcnt(4)" ::: "memory");
    } else {
      asm volatile("s_waitcnt vmcnt(0)" ::: "memory");
    }
    __builtin_amdgcn_s_barrier();
    asm volatile("" ::: "memory");
    const bf16* Ab = &As[cur][lq * 1024];
    const bf16* Bb = &Bs[cur][lq * 1024];
    short8 af[4], bfr[4];
    #pragma unroll
    for (int mi = 0; mi < 4; ++mi)
      af[mi] = *(const short8*)(Ab + (wr * 64 + mi * 16 + l15) * 8);
    #pragma unroll
    for (int ni = 0; ni < 4; ++ni)
      bfr[ni] = *(const short8*)(Bb + (wc * 64 + ni * 16 + l15) * 8);
    __builtin_amdgcn_s_setprio(1);
    #pragma unroll
    for (int mi = 0; mi < 4; ++mi)
      #pragma unroll
      for (int ni = 0; ni < 4; ++ni)
        acc[mi][ni] = __builtin_amdgcn_mfma_f32_16x16x32_bf16(bfr[ni], af[mi],
                                                              acc[mi][ni], 0, 0, 0);
    __builtin_amdgcn_s_setprio(0);
    asm volatile("" ::: "memory");
    __builtin_amdgcn_s_barrier();
  }

  #pragma unroll
  for (int ni = 0; ni < 4; ++ni) {
    int c0 = n0 + wc * 64 + ni * 16 + lq * 4;
    f32x4 bv = {};
    if (bias) bv = *(const f32x4*)(bias + c0);
    #pragma unroll
    for (int mi = 0; mi < 4; ++mi) {
      int row = m0 + wr * 64 + mi * 16 + l15;
      f32x4 v = acc[mi][ni] + bv;
      if (act == 1) {
        #pragma unroll
        for (int j = 0; j < 4; ++j) {
          float x = v[j];
          v[j] = 0.5f * x * (1.f + tanhf(0.79788456080286535f * (x + 0.044715f * x * x * x)));
        }
      } else if (act == 2) {
        #pragma unroll
        for (int j = 0; j < 4; ++j) v[j] = fmaxf(v[j], 0.f);
      }
      size_t idx = (size_t)row * N + c0;
      if (resid) v += *(const f32x4*)(resid + idx);
      if (outF) *(f32x4*)(outF + idx) = v;
      if (outB) *(short4v*)(outB + idx) = packbf4(v);
    }
  }
}

// ---------------------------------------------------------------------------
// Flash attention (non-split, used for SA). HD=96, NH=8.
// ---------------------------------------------------------------------------
__global__ __launch_bounds__(256) void flash_kernel(
    const bf16* __restrict__ Q, const bf16* __restrict__ Kp,
    const bf16* __restrict__ V, bf16* __restrict__ O,
    int Lk, int qRPB, int kRPB, int oRPB, int ld) {
  const float scale = 0.10206207261596575f;  // 1/sqrt(96)
  __shared__ bf16 Vt[96 * 72];
  __shared__ bf16 Ps[4 * 16 * 72];
  int tid = threadIdx.x, lane = tid & 63, w = tid >> 6;
  int l15 = lane & 15, lq = lane >> 4;
  int b = blockIdx.z, h = blockIdx.y, qt = blockIdx.x;
  int qbase = b * qRPB + qt * 64 + w * 16;
  int kbase = b * kRPB;
  int obase = b * oRPB + qt * 64 + w * 16;
  int ch = h * 96;

  short8 aQ[3];
  #pragma unroll
  for (int kd = 0; kd < 3; ++kd)
    aQ[kd] = *(const short8*)(Q + (size_t)(qbase + l15) * ld + ch + kd * 32 + lq * 8);

  f32x4 oacc[6] = {};
  float mrun[4] = {-1e30f, -1e30f, -1e30f, -1e30f};
  float lrun[4] = {0.f, 0.f, 0.f, 0.f};

  for (int kc = 0; kc < Lk; kc += 64) {
    for (int u = tid; u < 768; u += 256) {
      int kk = u / 12, dc = u % 12;
      short8 v = *(const short8*)(V + (size_t)(kbase + kc + kk) * ld + ch + dc * 8);
      const bf16* pv = (const bf16*)&v;
      #pragma unroll
      for (int e = 0; e < 8; ++e) Vt[(dc * 8 + e) * 72 + kk] = pv[e];
    }
    __syncthreads();

    f32x4 sacc[4] = {};
    #pragma unroll
    for (int ni = 0; ni < 4; ++ni)
      #pragma unroll
      for (int kd = 0; kd < 3; ++kd) {
        short8 bK = *(const short8*)(Kp + (size_t)(kbase + kc + ni * 16 + l15) * ld +
                                     ch + kd * 32 + lq * 8);
        sacc[ni] = __builtin_amdgcn_mfma_f32_16x16x32_bf16(aQ[kd], bK, sacc[ni], 0, 0, 0);
      }
    #pragma unroll
    for (int ni = 0; ni < 4; ++ni)
      #pragma unroll
      for (int j = 0; j < 4; ++j) sacc[ni][j] *= scale;

    float al[4];
    #pragma unroll
    for (int j = 0; j < 4; ++j) {
      float mx = fmaxf(fmaxf(sacc[0][j], sacc[1][j]), fmaxf(sacc[2][j], sacc[3][j]));
      #pragma unroll
      for (int off = 1; off < 16; off <<= 1) mx = fmaxf(mx, __shfl_xor(mx, off));
      float mnew = fmaxf(mrun[j], mx);
      float alpha = __expf(mrun[j] - mnew);
      float rsum = 0.f;
      #pragma unroll
      for (int ni = 0; ni < 4; ++ni) {
        float p = __expf(sacc[ni][j] - mnew);
        sacc[ni][j] = p;
        rsum += p;
      }
      #pragma unroll
      for (int off = 1; off < 16; off <<= 1) rsum += __shfl_xor(rsum, off);
      lrun[j] = lrun[j] * alpha + rsum;
      mrun[j] = mnew;
      al[j] = alpha;
    }

    #pragma unroll
    for (int ni = 0; ni < 4; ++ni)
      #pragma unroll
      for (int j = 0; j < 4; ++j)
        Ps[(w * 16 + lq * 4 + j) * 72 + ni * 16 + l15] = __float2bfloat16(sacc[ni][j]);
    #pragma unroll
    for (int t = 0; t < 6; ++t)
      #pragma unroll
      for (int j = 0; j < 4; ++j) oacc[t][j] *= al[j];
    short8 aP[2];
    #pragma unroll
    for (int ks = 0; ks < 2; ++ks)
      aP[ks] = *(const short8*)(&Ps[(w * 16 + l15) * 72 + ks * 32 + lq * 8]);
    #pragma unroll
    for (int t = 0; t < 6; ++t)
      #pragma unroll
      for (int ks = 0; ks < 2; ++ks) {
        short8 bV = *(const short8*)(&Vt[(t * 16 + l15) * 72 + ks * 32 + lq * 8]);
        oacc[t] = __builtin_amdgcn_mfma_f32_16x16x32_bf16(aP[ks], bV, oacc[t], 0, 0, 0);
      }
    __syncthreads();
  }

  #pragma unroll
  for (int t = 0; t < 6; ++t)
    #pragma unroll
    for (int j = 0; j < 4; ++j) {
      int row = obase + lq * 4 + j;
      int col = ch + t * 16 + l15;
      O[(size_t)row * 768 + col] = __float2bfloat16(oacc[t][j] / lrun[j]);
    }
}

// ---------------------------------------------------------------------------
// Split-K flash for cross-attention (broadcast latent Q, 64 rows/batch).
// ---------------------------------------------------------------------------
__global__ __launch_bounds__(256) void flash_split_kernel(
    const bf16* __restrict__ Q, const bf16* __restrict__ Kp,
    const bf16* __restrict__ V, float* __restrict__ Opart,
    float* __restrict__ Mpart, float* __restrict__ Lpart,
    int splitLen, int kRPB) {
  const float scale = 0.10206207261596575f;
  __shared__ bf16 Vt[96 * 72];
  __shared__ bf16 Ps[4 * 16 * 72];
  int tid = threadIdx.x, lane = tid & 63, w = tid >> 6;
  int l15 = lane & 15, lq = lane >> 4;
  int s = blockIdx.x, h = blockIdx.y, b = blockIdx.z;
  int kbase = b * kRPB + s * splitLen;
  int ch = h * 96;

  short8 aQ[3];
  #pragma unroll
  for (int kd = 0; kd < 3; ++kd)
    aQ[kd] = *(const short8*)(Q + (size_t)(w * 16 + l15) * 768 + ch + kd * 32 + lq * 8);

  f32x4 oacc[6] = {};
  float mrun[4] = {-1e30f, -1e30f, -1e30f, -1e30f};
  float lrun[4] = {0.f, 0.f, 0.f, 0.f};

  for (int kc = 0; kc < splitLen; kc += 64) {
    for (int u = tid; u < 768; u += 256) {
      int kk = u / 12, dc = u % 12;
      short8 v = *(const short8*)(V + (size_t)(kbase + kc + kk) * 768 + ch + dc * 8);
      const bf16* pv = (const bf16*)&v;
      #pragma unroll
      for (int e = 0; e < 8; ++e) Vt[(dc * 8 + e) * 72 + kk] = pv[e];
    }
    __syncthreads();

    f32x4 sacc[4] = {};
    #pragma unroll
    for (int ni = 0; ni < 4; ++ni)
      #pragma unroll
      for (int kd = 0; kd < 3; ++kd) {
        short8 bK = *(const short8*)(Kp + (size_t)(kbase + kc + ni * 16 + l15) * 768 +
                                     ch + kd * 32 + lq * 8);
        sacc[ni] = __builtin_amdgcn_mfma_f32_16x16x32_bf16(aQ[kd], bK, sacc[ni], 0, 0, 0);
      }
    #pragma unroll
    for (int ni = 0; ni < 4; ++ni)
      #pragma unroll
      for (int j = 0; j < 4; ++j) sacc[ni][j] *= scale;

    float al[4];
    #pragma unroll
    for (int j = 0; j < 4; ++j) {
      float mx = fmaxf(fmaxf(sacc[0][j], sacc[1][j]), fmaxf(sacc[2][j], sacc[3][j]));
      #pragma unroll
      for (int off = 1; off < 16; off <<= 1) mx = fmaxf(mx, __shfl_xor(mx, off));
      float mnew = fmaxf(mrun[j], mx);
      float alpha = __expf(mrun[j] - mnew);
      float rsum = 0.f;
      #pragma unroll
      for (int ni = 0; ni < 4; ++ni) {
        float p = __expf(sacc[ni][j] - mnew);
        sacc[ni][j] = p;
        rsum += p;
      }
      #pragma unroll
      for (int off = 1; off < 16; off <<= 1) rsum += __shfl_xor(rsum, off);
      lrun[j] = lrun[j] * alpha + rsum;
      mrun[j] = mnew;
      al[j] = alpha;
    }

    #pragma unroll
    for (int ni = 0; ni < 4; ++ni)
      #pragma unroll
      for (int j = 0; j < 4; ++j)
        Ps[(w * 16 + lq * 4 + j) * 72 + ni * 16 + l15] = __float2bfloat16(sacc[ni][j]);
    #pragma unroll
    for (int t = 0; t < 6; ++t)
      #pragma unroll
      for (int j = 0; j < 4; ++j) oacc[t][j] *= al[j];
    short8 aP[2];
    #pragma unroll
    for (int ks = 0; ks < 2; ++ks)
      aP[ks] = *(const short8*)(&Ps[(w * 16 + l15) * 72 + ks * 32 + lq * 8]);
    #pragma unroll
    for (int t = 0; t < 6; ++t)
      #pragma unroll
      for (int ks = 0; ks < 2; ++ks) {
        short8 bV = *(const short8*)(&Vt[(t * 16 + l15) * 72 + ks * 32 + lq * 8]);
        oacc[t] = __builtin_amdgcn_mfma_f32_16x16x32_bf16(aP[ks], bV, oacc[t], 0, 0, 0);
      }
    __syncthreads();
  }

  int orow = b * 64 + w * 16;
  #pragma unroll
  for (int t = 0; t < 6; ++t)
    #pragma unroll
    for (int j = 0; j < 4; ++j)
      Opart[(size_t)(s * 1024 + orow + lq * 4 + j) * 768 + ch + t * 16 + l15] = oacc[t][j];
  if (l15 == 0) {
    #pragma unroll
    for (int j = 0; j < 4; ++j) {
      int qqi = w * 16 + lq * 4 + j;
      int mi = ((s * 16 + b) * 8 + h) * 64 + qqi;
      Mpart[mi] = mrun[j];
      Lpart[mi] = lrun[j];
    }
  }
}

__global__ __launch_bounds__(256) void flash_merge_kernel(
    const float* __restrict__ Opart, const float* __restrict__ Mpart,
    const float* __restrict__ Lpart, bf16* __restrict__ O, int nsplit) {
  int row = blockIdx.x;   // b*64+q
  int tid = threadIdx.x;
  int c0 = tid * 3;
  int b = row >> 6, q = row & 63;
  int h = c0 / 96;
  float m = -1e30f;
  for (int s = 0; s < nsplit; ++s)
    m = fmaxf(m, Mpart[((s * 16 + b) * 8 + h) * 64 + q]);
  float l = 0.f, o0 = 0.f, o1 = 0.f, o2 = 0.f;
  for (int s = 0; s < nsplit; ++s) {
    int mi = ((s * 16 + b) * 8 + h) * 64 + q;
    float ws = __expf(Mpart[mi] - m);
    l += ws * Lpart[mi];
    const float* op = Opart + (size_t)(s * 1024 + row) * 768 + c0;
    o0 += ws * op[0]; o1 += ws * op[1]; o2 += ws * op[2];
  }
  float inv = 1.f / l;
  size_t ob = (size_t)row * 768 + c0;
  O[ob]     = __float2bfloat16(o0 * inv);
  O[ob + 1] = __float2bfloat16(o1 * inv);
  O[ob + 2] = __float2bfloat16(o2 * inv);
}

// ---------------------------------------------------------------------------
extern "C" void kernel_launch(void* const* d_in, const int* in_sizes, int n_in,
                              void* d_out, int out_size, void* d_ws, size_t ws_size,
                              hipStream_t stream) {
  const float* frames = (const float*)d_in[0];
  const float* pe_w   = (const float*)d_in[1];
  const float* pe_b   = (const float*)d_in[2];
  const float* latents= (const float*)d_in[3];
  const float* ca_qw  = (const float*)d_in[4];  const float* ca_qb = (const float*)d_in[5];
  const float* ca_kw  = (const float*)d_in[6];  const float* ca_kb = (const float*)d_in[7];
  const float* ca_vw  = (const float*)d_in[8];  const float* ca_vb = (const float*)d_in[9];
  const float* ca_ow  = (const float*)d_in[10]; const float* ca_ob = (const float*)d_in[11];
  const float* nq_g   = (const float*)d_in[12]; const float* nq_b  = (const float*)d_in[13];
  const float* nkv_g  = (const float*)d_in[14]; const float* nkv_b = (const float*)d_in[15];
  const float* no_g   = (const float*)d_in[16]; const float* no_b  = (const float*)d_in[17];
  const float* m1_w   = (const float*)d_in[18]; const float* m1_b  = (const float*)d_in[19];
  const float* m2_w   = (const float*)d_in[20]; const float* m2_b  = (const float*)d_in[21];
  const float* sa_qw  = (const float*)d_in[22]; const float* sa_qb = (const float*)d_in[23];
  const float* sa_kw  = (const float*)d_in[24]; const float* sa_kb = (const float*)d_in[25];
  const float* sa_vw  = (const float*)d_in[26]; const float* sa_vb = (const float*)d_in[27];
  const float* sa_ow  = (const float*)d_in[28]; const float* sa_ob = (const float*)d_in[29];
  const float* f1_w   = (const float*)d_in[30]; const float* f1_b  = (const float*)d_in[31];
  const float* f2_w   = (const float*)d_in[32]; const float* f2_b  = (const float*)d_in[33];
  const float* n1_g   = (const float*)d_in[34]; const float* n1_b  = (const float*)d_in[35];
  const float* n2_g   = (const float*)d_in[36]; const float* n2_b  = (const float*)d_in[37];

  char* ws = (char*)d_ws;
  size_t off = 0;
  auto take = [&](size_t bytes) -> char* {
    char* p = ws + off;
    off += (bytes + 255) & ~(size_t)255;
    return p;
  };

  // persistent bf16 weights
  bf16* w_pe   = (bf16*)take((size_t)768 * 640 * 2);
  bf16* w_caq  = (bf16*)take((size_t)768 * 768 * 2);
  bf16* w_cakv = (bf16*)take((size_t)1536 * 768 * 2);  // [V(768); K'(768)] rows
  bf16* w_cao  = (bf16*)take((size_t)768 * 768 * 2);
  bf16* w_m1   = (bf16*)take((size_t)3072 * 768 * 2);
  bf16* w_m2   = (bf16*)take((size_t)768 * 3072 * 2);
  bf16* w_saq  = (bf16*)take((size_t)768 * 768 * 2);   // contiguous with sak/sav
  bf16* w_sak  = (bf16*)take((size_t)768 * 768 * 2);
  bf16* w_sav  = (bf16*)take((size_t)768 * 768 * 2);
  bf16* w_sao  = (bf16*)take((size_t)768 * 768 * 2);
  bf16* w_f1   = (bf16*)take((size_t)1536 * 768 * 2);
  bf16* w_f2   = (bf16*)take((size_t)768 * 1536 * 2);
  float* sab_cat = (float*)take((size_t)2304 * 4);
  float* s1v  = (float*)take((size_t)768 * 4);
  float* s2v  = (float*)take((size_t)768 * 4);
  float* muv  = (float*)take((size_t)32768 * 4);
  float* rsv  = (float*)take((size_t)32768 * 4);

  bf16* q_ln = (bf16*)take((size_t)128 * 768 * 2);
  bf16* qh   = (bf16*)take((size_t)128 * 768 * 2);

  bf16* kv   = (bf16*)take((size_t)32768 * 768 * 2);   // raw patch tokens
  // vh & kh in ONE contiguous take; imcol (32768x640 bf16 = 41.9MB) aliases it
  bf16* vhkh = (bf16*)take((size_t)2 * 32768 * 768 * 2);
  bf16* vh = vhkh;
  bf16* kh = vhkh + (size_t)32768 * 768;
  bf16* imcol = vhkh;  // dead after patch GEMM, before vh/kh are written

  // union region: CA split partials / stage-2/3 activations
  const size_t REGION = (size_t)32768 * 608 * 2;  // 39,845,888
  char* region = take(REGION);
  float* Opart = (float*)region;                          // 25,165,824 B
  float* Mpart = (float*)(region + 25165824);             //    262,144 B
  float* Lpart = (float*)(region + 25165824 + 262144);    //    262,144 B
  bf16*  attn_o = (bf16*)(region + REGION - (size_t)1024 * 768 * 2);
  size_t ro = 0;
  auto rtake = [&](size_t bytes) -> char* {
    char* p = region + ro;
    ro += (bytes + 255) & ~(size_t)255;
    return p;
  };
  float* out_f  = (float*)rtake((size_t)1024 * 768 * 4);
  bf16*  h_b    = (bf16*)rtake((size_t)1024 * 768 * 2);
  bf16*  g_b    = (bf16*)rtake((size_t)1024 * 3072 * 2);
  float* tok_f  = (float*)rtake((size_t)1024 * 768 * 4);
  bf16*  tok_b  = (bf16*)rtake((size_t)1024 * 768 * 2);
  bf16*  xqkv   = (bf16*)rtake((size_t)1024 * 2304 * 2);
  bf16*  sa_o   = (bf16*)rtake((size_t)1024 * 768 * 2);
  float* y_f    = (float*)rtake((size_t)1024 * 768 * 4);
  float* x1f    = (float*)rtake((size_t)1024 * 768 * 4);
  bf16*  x1b    = (bf16*)rtake((size_t)1024 * 768 * 2);
  bf16*  ff1    = (bf16*)rtake((size_t)1024 * 1536 * 2);
  float* z_f    = (float*)rtake((size_t)1024 * 768 * 4);
  (void)ws_size; (void)in_sizes; (void)n_in; (void)out_size;

  // 1) fused preprocessing: prepack + im2col + s12 + LN(latents) + concat3
  Segs segs;
  segs.s[0]  = {pe_w,  w_pe,  768, 588, 640, nullptr};
  segs.s[1]  = {ca_qw, w_caq, 768, 768, 768, nullptr};
  segs.s[2]  = {ca_vw, w_cakv, 768, 768, 768, nullptr};
  segs.s[3]  = {ca_kw, w_cakv + (size_t)768 * 768, 768, 768, 768, nkv_g};
  segs.s[4]  = {ca_ow, w_cao, 768, 768, 768, nullptr};
  segs.s[5]  = {m1_w,  w_m1,  3072, 768, 768, nullptr};
  segs.s[6]  = {m2_w,  w_m2,  768, 3072, 3072, nullptr};
  segs.s[7]  = {sa_qw, w_saq, 768, 768, 768, nullptr};
  segs.s[8]  = {sa_kw, w_sak, 768, 768, 768, nullptr};
  segs.s[9]  = {sa_vw, w_sav, 768, 768, 768, nullptr};
  segs.s[10] = {f1_w,  w_f1,  1536, 768, 768, nullptr};
  segs.s[11] = {f2_w,  w_f2,  768, 1536, 1536, nullptr};
  segs.s[12] = {sa_ow, w_sao, 768, 768, 768, nullptr};
  preproc_kernel<<<41097, 256, 0, stream>>>(
      segs, frames, imcol,
      ca_kw, nkv_g, nkv_b, ca_kb, s1v, s2v,
      latents, nq_g, nq_b, q_ln,
      sa_qb, sa_kb, sa_vb, sab_cat);

  // 2) patch-embed GEMM (256^2, phase-split) -> kv
  gemm256<<<dim3(3, 128), 512, 0, stream>>>(imcol, w_pe, pe_b, kv,
                                            32768, 768, 640, 0,
                                            nullptr, nullptr, nullptr, nullptr, nullptr);

  // 3) Q projection (small)
  gemm_bf16<<<dim3(6, 1), 256, 0, stream>>>(q_ln, w_caq, ca_qb, nullptr, nullptr, qh,
                                            128, 768, 768, 0);

  // 4) per-row LN stats of kv
  rowstats_kernel<<<8192, 256, 0, stream>>>(kv, muv, rsv);

  // 5) merged V + fused-LN-K projection (256^2, phase-split) -> vh, kh
  gemm256<<<dim3(6, 128), 512, 0, stream>>>(kv, w_cakv, ca_vb, vh,
                                            32768, 1536, 768, 3,
                                            muv, rsv, s1v, s2v, kh);

  // 6) cross-attention split-K
  flash_split_kernel<<<dim3(8, 8, 16), 256, 0, stream>>>(qh, kh, vh, Opart, Mpart, Lpart,
                                                         256, 2048);
  flash_merge_kernel<<<1024, 256, 0, stream>>>(Opart, Mpart, Lpart, attn_o, 8);

  // 7) O projection -> out_f
  gemm_bf16<<<dim3(6, 8), 256, 0, stream>>>(attn_o, w_cao, ca_ob, nullptr, out_f, nullptr,
                                            1024, 768, 768, 0);

  // 8) LN(out) -> h_b
  ln_kernel<<<1024, 256, 0, stream>>>(out_f, nullptr, no_g, no_b, nullptr, h_b, 1024);

  // 9) MLP up + GELU
  gemm_bf16<<<dim3(24, 8), 256, 0, stream>>>(h_b, w_m1, m1_b, nullptr, nullptr, g_b,
                                             1024, 3072, 768, 1);

  // 10) MLP down + residual
  gemm_bf16<<<dim3(6, 8), 256, 0, stream>>>(g_b, w_m2, m2_b, out_f, tok_f, tok_b,
                                            1024, 768, 3072, 0);

  // 11) merged SA Q/K/V projection -> xqkv [1024][2304]
  gemm_bf16<<<dim3(18, 8), 256, 0, stream>>>(tok_b, w_saq, sab_cat, nullptr, nullptr, xqkv,
                                             1024, 2304, 768, 0);

  // 12) self-attention
  flash_kernel<<<dim3(4, 8, 4), 256, 0, stream>>>(xqkv, xqkv + 768, xqkv + 1536, sa_o,
                                                  256, 256, 256, 256, 2304);

  // 13) SA O-projection + residual(tok)
  gemm_bf16<<<dim3(6, 8), 256, 0, stream>>>(sa_o, w_sao, sa_ob, tok_f, y_f, nullptr,
                                            1024, 768, 768, 0);

  // 14) LN n1
  ln_kernel<<<1024, 256, 0, stream>>>(y_f, nullptr, n1_g, n1_b, x1f, x1b, 1024);

  // 15) FF up + ReLU
  gemm_bf16<<<dim3(12, 8), 256, 0, stream>>>(x1b, w_f1, f1_b, nullptr, nullptr, ff1,
                                             1024, 1536, 768, 2);

  // 16) FF down + residual(x1)
  gemm_bf16<<<dim3(6, 8), 256, 0, stream>>>(ff1, w_f2, f2_b, x1f, z_f, nullptr,
                                            1024, 768, 1536, 0);

  // 17) LN n2 -> d_out
  ln_kernel<<<1024, 256, 0, stream>>>(z_f, nullptr, n2_g, n2_b, (float*)d_out, nullptr, 1024);
}